// Round 13
// baseline (3411.871 us; speedup 1.0000x reference)
//
#include <hip/hip_runtime.h>
#include <hip/hip_fp16.h>

#define Hh 1024
#define H2 2048
#define NB 16
#define MAXN 376
#define NSTAGE 125

__device__ __forceinline__ float gelu_f(float x) {
    return 0.5f * x * (1.0f + erff(x * 0.70710678118654752440f));
}

// ---------------- float -> half conversion (weights into workspace) ----------------
__global__ __launch_bounds__(256) void kcvt(const float* __restrict__ src,
                                            __half* __restrict__ dst, int n) {
    int i = blockIdx.x * 256 + threadIdx.x;
    int stride = gridDim.x * 256;
    for (; i < n; i += stride) dst[i] = __float2half(src[i]);
}

// ---------------- warm: stream both weight arrays into L2/L3 ----------------
__global__ __launch_bounds__(256) void kwarm(const uint4* __restrict__ a,
                                             const uint4* __restrict__ b,
                                             int n16, float* __restrict__ sink) {
    int i = blockIdx.x * 256 + threadIdx.x;
    int s = gridDim.x * 256;
    unsigned acc = 0;
    for (int j = i; j < n16; j += s) { uint4 x = a[j]; uint4 y = b[j]; acc ^= x.x ^ y.x; }
    if (acc == 0xdeadbeefu) sink[0] = 1.f;   // never true; keeps loads live
}

// ---------------- K0a: tmp[b][o] = gelu( concat(p,c) @ Wte + bte ) ----------------
__global__ __launch_bounds__(256) void k0a(const float* __restrict__ Wte,
                                           const float* __restrict__ bte,
                                           const float* __restrict__ pe,
                                           const float* __restrict__ cte,
                                           float* __restrict__ tmp) {
    __shared__ float red[8][8][33];
    int tid = threadIdx.x;
    int ob = blockIdx.x & 31, bg = blockIdx.x >> 5;
    int o_l = tid & 31, kc = tid >> 5;     // 32 outputs x 8 k-chunks
    int o = ob * 32 + o_l;
    float acc[8] = {0.f,0.f,0.f,0.f,0.f,0.f,0.f,0.f};
    const float* src = (kc < 4) ? pe : cte;
    int koff = (kc < 4) ? 0 : 1024;
    int k0 = kc * 256;
    for (int k = k0; k < k0 + 256; k += 4) {
        float w0 = Wte[(size_t)(k + 0) * Hh + o];
        float w1 = Wte[(size_t)(k + 1) * Hh + o];
        float w2 = Wte[(size_t)(k + 2) * Hh + o];
        float w3 = Wte[(size_t)(k + 3) * Hh + o];
#pragma unroll
        for (int bb = 0; bb < 8; ++bb) {
            int b = bg * 8 + bb;
            const float4 x4 = *(const float4*)(src + (size_t)b * Hh + (k - koff));
            acc[bb] = fmaf(w3, x4.w, fmaf(w2, x4.z, fmaf(w1, x4.y, fmaf(w0, x4.x, acc[bb]))));
        }
    }
#pragma unroll
    for (int bb = 0; bb < 8; ++bb) red[kc][bb][o_l] = acc[bb];
    __syncthreads();
    int o2 = tid & 31, bb2 = tid >> 5;
    float s = 0.f;
#pragma unroll
    for (int q = 0; q < 8; ++q) s += red[q][bb2][o2];
    int og = ob * 32 + o2;
    int b = bg * 8 + bb2;
    tmp[(size_t)b * Hh + og] = gelu_f(s + bte[og]);
}

// ---------------- K0b: LayerNorm + root value + state init (one block per b) ----------------
__global__ __launch_bounds__(256) void k0b(const float* __restrict__ tmp,
                                           const float* __restrict__ g,
                                           const float* __restrict__ bl,
                                           const float* __restrict__ wv,
                                           const float* __restrict__ bv,
                                           float* __restrict__ emb,
                                           float* __restrict__ vals,
                                           int* __restrict__ visits,
                                           int* __restrict__ nbuf,
                                           int* __restrict__ curbuf,
                                           float* __restrict__ vacc) {
    __shared__ float red[256];
    int b = blockIdx.x, tid = threadIdx.x;
    for (int q = tid; q < MAXN; q += 256) {
        if (q > 0) { vals[b * MAXN + q] = 0.f; visits[b * MAXN + q] = 0; }
    }
    if (b == 0 && tid < 96) vacc[tid] = 0.f;   // both ping-pong accumulator slots
    float4 v = *(const float4*)(tmp + (size_t)b * Hh + tid * 4);
    red[tid] = (v.x + v.y) + (v.z + v.w);
    __syncthreads();
    for (int st = 128; st > 0; st >>= 1) { if (tid < st) red[tid] += red[tid + st]; __syncthreads(); }
    float mu = red[0] * (1.0f / 1024.0f);
    __syncthreads();
    float dx0 = v.x - mu, dx1 = v.y - mu, dx2 = v.z - mu, dx3 = v.w - mu;
    red[tid] = (dx0 * dx0 + dx1 * dx1) + (dx2 * dx2 + dx3 * dx3);
    __syncthreads();
    for (int st = 128; st > 0; st >>= 1) { if (tid < st) red[tid] += red[tid + st]; __syncthreads(); }
    float var = red[0] * (1.0f / 1024.0f);
    __syncthreads();
    float rs = rsqrtf(var + 1e-5f);
    int d0 = tid * 4;
    float r0 = g[d0 + 0] * (dx0 * rs) + bl[d0 + 0];
    float r1 = g[d0 + 1] * (dx1 * rs) + bl[d0 + 1];
    float r2 = g[d0 + 2] * (dx2 * rs) + bl[d0 + 2];
    float r3 = g[d0 + 3] * (dx3 * rs) + bl[d0 + 3];
    float4 ro; ro.x = r0; ro.y = r1; ro.z = r2; ro.w = r3;
    *(float4*)(emb + (size_t)b * MAXN * Hh + d0) = ro;
    red[tid] = (r0 * wv[d0] + r1 * wv[d0 + 1]) + (r2 * wv[d0 + 2] + r3 * wv[d0 + 3]);
    __syncthreads();
    for (int st = 128; st > 0; st >>= 1) { if (tid < st) red[tid] += red[tid + st]; __syncthreads(); }
    if (tid == 0) {
        vals[b * MAXN] = red[0] + bv[0];
        visits[b * MAXN] = 1;
        nbuf[b] = 1;          // state slot 0
        curbuf[b] = 0;
    }
}

// ---------------- K1: (optional folded dead-stage transition) + select + mv1 -> hbuf ----------------
// W1h fp16 [6144][1024]; block owns 4 rows; thread (row=tid>>6, kpos=tid&63).
// fold==1: perform dead transition (apply expansion + backprop + cur<-0) LOCALLY (no global
// writes to vals/visits here; k_mv2 commits them), then d==1 selection on local node 0..3 state.
__global__ __launch_bounds__(256) void k_mv1(const __half* __restrict__ W1h,
                                             const float* __restrict__ b1,
                                             const float* __restrict__ emb,
                                             float* __restrict__ hbuf,
                                             const float* __restrict__ vin,
                                             float* __restrict__ vout,
                                             float* vals, int* visits,
                                             const int* __restrict__ nin,
                                             const int* __restrict__ curin,
                                             int* __restrict__ nout,
                                             int* __restrict__ curout,
                                             const float* __restrict__ bv, int t, int fold) {
    __shared__ float red[64][4][17];
    __shared__ int curL[NB];
    __shared__ int exS;
    int tid = threadIdx.x;
    int d = t % 5;
    if (blockIdx.x == 0 && tid < 48) vout[tid] = 0.f;
    // ---- hoisted weight loads ----
    int row = tid >> 6, kpos = tid & 63;
    int o = blockIdx.x * 4 + row;           // [0, 6144)
    const __half* wp = W1h + (size_t)o * Hh;
    uint4 wl0 = *(const uint4*)(wp + kpos * 8);
    uint4 wl1 = *(const uint4*)(wp + 512 + kpos * 8);
    if (tid == 0) exS = 0;
    __syncthreads();
    if (tid < NB) {
        int b = tid;
        int n_old = nin[b], cur_old = curin[b];
        float val03[4]; int vis03[4];
        bool lcl = false;
        if (fold) {
            // dead-stage transition, replicated locally in every block
            bool epA = (n_old - 1) < (cur_old + 1) * 3;
            float a0 = 0.f, a1 = 0.f, a2 = 0.f;
            if (epA) { a0 = bv[0] + vin[b*3+0]; a1 = bv[0] + vin[b*3+1]; a2 = bv[0] + vin[b*3+2]; }
            int nA = n_old + (epA ? 3 : 0);
#pragma unroll
            for (int i = 0; i < 4; ++i) { val03[i] = vals[b*MAXN+i]; vis03[i] = visits[b*MAXN+i]; }
            int leaf = min(cur_old, nA - 1);
            int jl = leaf - n_old;
            float lv;
            if (epA && jl >= 0 && jl < 3) lv = (jl == 0) ? a0 : ((jl == 1) ? a1 : a2);
            else lv = vals[b*MAXN + min(leaf, MAXN-1)];
            int node = leaf;
#pragma unroll
            for (int it2 = 0; it2 < 8; ++it2) {
                if (node > 0) {
                    int p = (node - 1) / 3;
                    int pc; float pvv;
                    if (p < 4) { pc = vis03[p]; pvv = val03[p]; }
                    else { pc = visits[b*MAXN+p]; pvv = vals[b*MAXN+p]; }
                    float pcf = (float)pc;
                    float nvv = (pvv * pcf + lv) / (pcf + 1.0f);
                    if (p < 4) { val03[p] = nvv; vis03[p] = pc + 1; }
                    node = p;
                }
            }
            n_old = nA; cur_old = 0; lcl = true;
            // leaf >= 4 always here (n>=7), so vis03 unaffected by visits[leaf]+=1
        }
        int n_new = n_old;
        bool ep = false;
        float vnew0 = 0.f, vnew1 = 0.f, vnew2 = 0.f;
        if (t > 0 && !fold) {
            ep = (n_old - 1) < (cur_old + 1) * 3;
            if (ep) {
                vnew0 = bv[0] + vin[b*3+0];
                vnew1 = bv[0] + vin[b*3+1];
                vnew2 = bv[0] + vin[b*3+2];
                n_new += 3;
            }
        }
        int cur_new = 0;
        const float* vb = vals + b * MAXN;
        const int* tb = visits + b * MAXN;
        if (d != 0) {
            int pv = 0;
#pragma unroll
            for (int i = 0; i < 3; ++i) {
                int pidx = 3 * cur_old + i;
                if (pidx < n_new) {
                    int safe = min(pidx, MAXN - 1);
                    int jj = safe - n_old;
                    int vis;
                    if (ep && jj >= 0 && jj < 3) vis = 1;
                    else if (lcl && safe < 4) vis = vis03[safe];
                    else vis = tb[safe];
                    pv += vis;
                }
            }
            float log_pv = logf((float)(pv > 1 ? pv : 1));
            float best = -INFINITY; int best_idx = cur_old;
#pragma unroll
            for (int ci = 0; ci < 3; ++ci) {
                int child = 3 * cur_old + 1 + ci;
                int safe = min(child, MAXN - 1);
                int jj = safe - n_old;
                float v; int cn;
                if (ep && jj >= 0 && jj < 3) {
                    v = (jj == 0) ? vnew0 : ((jj == 1) ? vnew1 : vnew2);
                    cn = 1;
                } else if (lcl && safe < 4) {
                    v = val03[safe]; cn = vis03[safe];
                } else { v = vb[safe]; cn = tb[safe]; }
                float cnf = (float)(cn > 1 ? cn : 1);
                float ucb = v + 1.414f * sqrtf(log_pv / cnf);
                if (child < n_new && ucb > best) { best = ucb; best_idx = child; }
            }
            cur_new = best_idx;
        }
        // (d==0 && t>0 dead-stage path no longer dispatched as its own kernel)
        bool ex = (n_new - 1) < (cur_new + 1) * 3;
        curL[b] = cur_new;
        if (ex) atomicOr(&exS, 1 << b);
        if (blockIdx.x == 0) {
            nout[b] = n_new; curout[b] = cur_new;
            if (ep) {
                if (n_old + 0 < MAXN) { vals[b * MAXN + n_old + 0] = vnew0; visits[b * MAXN + n_old + 0] = 1; }
                if (n_old + 1 < MAXN) { vals[b * MAXN + n_old + 1] = vnew1; visits[b * MAXN + n_old + 1] = 1; }
                if (n_old + 2 < MAXN) { vals[b * MAXN + n_old + 2] = vnew2; visits[b * MAXN + n_old + 2] = 1; }
            }
        }
    }
    __syncthreads();
    unsigned em = (unsigned)exS;
    float acc[16];
#pragma unroll
    for (int b = 0; b < 16; ++b) acc[b] = 0.f;
    if (em) {
        const float4* xp[16];
#pragma unroll
        for (int b = 0; b < 16; ++b)
            xp[b] = (const float4*)(emb + (size_t)(b * MAXN + curL[b]) * Hh);
        union { uint4 u; __half h[8]; } wu[2];
        wu[0].u = wl0; wu[1].u = wl1;
#pragma unroll
        for (int j = 0; j < 2; ++j) {
            float wf[8];
#pragma unroll
            for (int r = 0; r < 8; ++r) wf[r] = __half2float(wu[j].h[r]);
            int f4 = j * 128 + kpos * 2;
#pragma unroll
            for (int b = 0; b < 16; ++b) {
                if (em & (1u << b)) {
                    float4 xa = xp[b][f4];
                    float4 xb = xp[b][f4 + 1];
                    acc[b] = fmaf(wf[3], xa.w, fmaf(wf[2], xa.z, fmaf(wf[1], xa.y, fmaf(wf[0], xa.x, acc[b]))));
                    acc[b] = fmaf(wf[7], xb.w, fmaf(wf[6], xb.z, fmaf(wf[5], xb.y, fmaf(wf[4], xb.x, acc[b]))));
                }
            }
        }
    }
    {
        float* rp = red[kpos][row];
#pragma unroll
        for (int b = 0; b < 16; ++b) rp[b] = acc[b];
    }
    __syncthreads();
    if (tid < 64) {
        int row2 = tid >> 4, b2 = tid & 15;
        if (em & (1u << b2)) {
            float s = 0.f;
#pragma unroll
            for (int q = 0; q < 64; ++q) s += red[q][row2][b2];
            int og = blockIdx.x * 4 + row2;
            int w = og >> 11, ii = og & 2047;
            float hv = gelu_f(s + b1[og]);
            hbuf[(size_t)(b2 * 3 + w) * H2 + ii] = hv;
        }
    }
}

// ---------------- K2: commit folded dead transition (block 0) + mv2 + value atomicAdd ----------------
__global__ __launch_bounds__(256) void k_mv2(const __half* __restrict__ W2h,
                                             const float* __restrict__ b2p,
                                             const float* __restrict__ wv,
                                             const float* __restrict__ hbuf,
                                             float* __restrict__ emb,
                                             float* __restrict__ vacc,
                                             const int* __restrict__ nin,
                                             const int* __restrict__ curin,
                                             int foldA,
                                             const int* __restrict__ ninA,
                                             const int* __restrict__ curinA,
                                             const float* __restrict__ vinA,
                                             float* vals, int* visits,
                                             const float* __restrict__ bv) {
    __shared__ float red[128][2][17];
    __shared__ float prS[16][3];
    __shared__ int curL[NB], nL[NB];
    __shared__ int exS;
    int tid = threadIdx.x;
    // ---- commit the folded dead-stage transition (single writer, no same-kernel readers) ----
    if (foldA && blockIdx.x == 0 && tid < NB) {
        int b = tid;
        int nO = ninA[b], cO = curinA[b];
        bool epA = (nO - 1) < (cO + 1) * 3;
        if (epA) {
            float a0 = bv[0] + vinA[b*3+0];
            float a1 = bv[0] + vinA[b*3+1];
            float a2 = bv[0] + vinA[b*3+2];
            if (nO + 0 < MAXN) { vals[b*MAXN+nO+0] = a0; visits[b*MAXN+nO+0] = 1; }
            if (nO + 1 < MAXN) { vals[b*MAXN+nO+1] = a1; visits[b*MAXN+nO+1] = 1; }
            if (nO + 2 < MAXN) { vals[b*MAXN+nO+2] = a2; visits[b*MAXN+nO+2] = 1; }
        }
        int nA = nO + (epA ? 3 : 0);
        int leaf = min(cO, nA - 1);
        float lv = vals[b*MAXN + min(leaf, MAXN-1)];
        int node = leaf;
#pragma unroll
        for (int it2 = 0; it2 < 8; ++it2) {
            if (node > 0) {
                int p = (node - 1) / 3;
                int pc = visits[b*MAXN+p];
                float pcf = (float)pc;
                vals[b*MAXN+p] = (vals[b*MAXN+p] * pcf + lv) / (pcf + 1.0f);
                visits[b*MAXN+p] = pc + 1;
                node = p;
            }
        }
        visits[b*MAXN+leaf] += 1;
    }
    // ---- hoisted weight loads ----
    int row = tid >> 7, kpos = tid & 127;
    int o = blockIdx.x * 2 + row;            // [0, 3072)
    const __half* wp = W2h + (size_t)o * H2;
    uint4 wl0 = *(const uint4*)(wp + kpos * 8);
    uint4 wl1 = *(const uint4*)(wp + 1024 + kpos * 8);
    if (tid < NB) { curL[tid] = curin[tid]; nL[tid] = nin[tid]; }
    __syncthreads();
    if (tid == 0) {
        int m = 0;
        for (int b = 0; b < NB; ++b)
            if ((nL[b] - 1) < (curL[b] + 1) * 3) m |= 1 << b;
        exS = m;
    }
    __syncthreads();
    unsigned em = (unsigned)exS;
    int w = o >> 10;
    float acc[16];
#pragma unroll
    for (int b = 0; b < 16; ++b) acc[b] = 0.f;
    if (em) {
        const float4* hp[16];
#pragma unroll
        for (int b = 0; b < 16; ++b) hp[b] = (const float4*)(hbuf + (size_t)(b * 3 + w) * H2);
        union { uint4 u; __half h[8]; } wu[2];
        wu[0].u = wl0; wu[1].u = wl1;
#pragma unroll
        for (int j = 0; j < 2; ++j) {
            float wf[8];
#pragma unroll
            for (int r = 0; r < 8; ++r) wf[r] = __half2float(wu[j].h[r]);
            int f4 = j * 256 + kpos * 2;
#pragma unroll
            for (int b = 0; b < 16; ++b) {
                if (em & (1u << b)) {
                    float4 ha = hp[b][f4];
                    float4 hb = hp[b][f4 + 1];
                    acc[b] = fmaf(wf[3], ha.w, fmaf(wf[2], ha.z, fmaf(wf[1], ha.y, fmaf(wf[0], ha.x, acc[b]))));
                    acc[b] = fmaf(wf[7], hb.w, fmaf(wf[6], hb.z, fmaf(wf[5], hb.y, fmaf(wf[4], hb.x, acc[b]))));
                }
            }
        }
    }
    {
        float* rp = red[kpos][row];
#pragma unroll
        for (int b = 0; b < 16; ++b) rp[b] = acc[b];
    }
    __syncthreads();
    if (tid < 32) {
        int row2 = tid >> 4, b2 = tid & 15;
        int og = blockIdx.x * 2 + row2;
        int w2i = og >> 10, d2 = og & 1023;
        float pr = 0.f;
        if (em & (1u << b2)) {
            float s = 0.f;
#pragma unroll
            for (int q = 0; q < 128; ++q) s += red[q][row2][b2];
            float ce = emb[(size_t)(b2 * MAXN + curL[b2]) * Hh + d2];
            float nv = ce + 0.1f * (s + b2p[og]);
            int nidx = nL[b2] + w2i;
            if (nidx < MAXN) emb[(size_t)(b2 * MAXN + nidx) * Hh + d2] = nv;
            pr = nv * wv[d2];
        }
        prS[b2][row2] = pr;
    }
    __syncthreads();
    if (tid < NB) {
        if (em & (1u << tid)) {
            float s = prS[tid][0] + prS[tid][1];
            int wblk = (blockIdx.x * 2) >> 10;
            atomicAdd(&vacc[tid * 3 + wblk], s);
        }
    }
}

// ---------------- KF: final pending apply + backprop + argmax + outputs ----------------
__global__ __launch_bounds__(256) void kf(const float* __restrict__ emb,
                                          float* vals, int* visits,
                                          const int* __restrict__ nin,
                                          const int* __restrict__ curin,
                                          const float* __restrict__ vacc,
                                          const float* __restrict__ bv,
                                          float* __restrict__ out) {
    __shared__ int nF[NB];
    __shared__ float bval[NB];
    __shared__ int bidx[NB];
    __shared__ float redv[NB][16];
    __shared__ int redi[NB][16];
    __shared__ float mxS;
    int tid = threadIdx.x;
    if (tid < NB) {
        int b = tid;
        int n_old = nin[b], cur_old = curin[b];
        int n_new = n_old;
        bool ep = (n_old - 1) < (cur_old + 1) * 3;
        if (ep) {
            float vn0 = bv[0] + vacc[b * 3 + 0];
            float vn1 = bv[0] + vacc[b * 3 + 1];
            float vn2 = bv[0] + vacc[b * 3 + 2];
            if (n_old + 0 < MAXN) { vals[b * MAXN + n_old + 0] = vn0; visits[b * MAXN + n_old + 0] = 1; }
            if (n_old + 1 < MAXN) { vals[b * MAXN + n_old + 1] = vn1; visits[b * MAXN + n_old + 1] = 1; }
            if (n_old + 2 < MAXN) { vals[b * MAXN + n_old + 2] = vn2; visits[b * MAXN + n_old + 2] = 1; }
            n_new += 3;
        }
        int leaf = min(cur_old, n_new - 1);
        float lv = vals[b * MAXN + leaf];
        int node = leaf;
#pragma unroll
        for (int it = 0; it < 8; ++it) {
            if (node > 0) {
                int p = (node - 1) / 3;
                int pc = visits[b * MAXN + p];
                float pcf = (float)pc;
                vals[b * MAXN + p] = (vals[b * MAXN + p] * pcf + lv) / (pcf + 1.0f);
                visits[b * MAXN + p] = pc + 1;
                node = p;
            }
        }
        visits[b * MAXN + leaf] += 1;
        nF[b] = n_new;
    }
    __syncthreads();
    {
        int b = tid >> 4, q = tid & 15;
        float bv_ = -INFINITY; int bi_ = MAXN;
        int nn = nF[b];
        for (int idx = q; idx < MAXN; idx += 16) {
            float v = (idx < nn) ? vals[b * MAXN + idx] : -INFINITY;
            if (v > bv_ || (v == bv_ && idx < bi_)) { bv_ = v; bi_ = idx; }
        }
        redv[b][q] = bv_; redi[b][q] = bi_;
    }
    __syncthreads();
    if (tid < NB) {
        int b = tid;
        float bb = -INFINITY; int bi = MAXN;
        for (int q = 0; q < 16; ++q) {
            float v = redv[b][q]; int i2 = redi[b][q];
            if (v > bb || (v == bb && i2 < bi)) { bb = v; bi = i2; }
        }
        bval[b] = bb; bidx[b] = bi;
    }
    __syncthreads();
    if (tid == 0) {
        float m = bval[0];
        for (int b = 1; b < NB; ++b) m = fmaxf(m, bval[b]);
        mxS = m;
    }
    __syncthreads();
    if (tid < NB) {
        float c = bval[tid] / (mxS + 1e-8f);
        out[16384 + tid] = fminf(c, 1.0f);
        out[16400 + tid] = bval[tid];
    }
    for (int q2 = tid; q2 < 16384; q2 += 256) {
        int b = q2 >> 10, dd = q2 & 1023;
        out[q2] = emb[(size_t)(b * MAXN + bidx[b]) * Hh + dd];
    }
}

extern "C" void kernel_launch(void* const* d_in, const int* in_sizes, int n_in,
                              void* d_out, int out_size, void* d_ws, size_t ws_size,
                              hipStream_t stream) {
    const float* pe  = (const float*)d_in[0];
    const float* ce  = (const float*)d_in[1];
    const float* Wte = (const float*)d_in[2];
    const float* bte = (const float*)d_in[3];
    const float* gln = (const float*)d_in[4];
    const float* bln = (const float*)d_in[5];
    const float* wv  = (const float*)d_in[6];
    const float* bv  = (const float*)d_in[7];
    const float* W1  = (const float*)d_in[8];
    const float* b1  = (const float*)d_in[9];
    const float* W2  = (const float*)d_in[10];
    const float* b2  = (const float*)d_in[11];
    float* out = (float*)d_out;

    float* ws = (float*)d_ws;
    __half* W1h = (__half*)ws;             // 6144x1024 halfs (3145728 floats)
    __half* W2h = W1h + 6291456;           // 3072x2048 halfs (3145728 floats)
    float* embb = ws + 6291456;            // 16 x 376 x 1024
    float* hbuf = embb + 6160384;          // 16 x 3 x 2048
    float* vacc = hbuf + 98304;            // 2 slots x 16 x 3
    float* tmp  = vacc + 96;               // 16 x 1024
    float* vals = tmp + 16384;             // 16 x 376
    int* visits = (int*)(vals + 6016);     // 16 x 376
    int* nbuf   = visits + 6016;           // 3 x 16 (mod-3 state slots)
    int* curbuf = nbuf + 48;               // 3 x 16
    float* sink = (float*)(curbuf + 48);   // kwarm sink

    hipLaunchKernelGGL(kcvt, dim3(2048), dim3(256), 0, stream, W1, W1h, 6291456);
    hipLaunchKernelGGL(kcvt, dim3(2048), dim3(256), 0, stream, W2, W2h, 6291456);
    hipLaunchKernelGGL(kwarm, dim3(2048), dim3(256), 0, stream,
                       (const uint4*)W1h, (const uint4*)W2h, 786432, sink);

    hipLaunchKernelGGL(k0a, dim3(64), dim3(256), 0, stream, Wte, bte, pe, ce, tmp);
    hipLaunchKernelGGL(k0b, dim3(16), dim3(256), 0, stream, tmp, gln, bln, wv, bv,
                       embb, vals, visits, nbuf, curbuf, vacc);   // writes state slot 0

    int L = 0;
    for (int t = 0; t < NSTAGE; ++t) {
        if (t > 0 && t % 5 == 0) continue;         // dead stage folded into t+1
        int fold = (t % 5 == 1 && t > 1) ? 1 : 0;
        int rs = (fold ? (t - 1) : t) % 3;         // state read slot
        int wsS = (t + 1) % 3;                     // state write slot
        int vi = ((L + 1) & 1) * 48;               // == (L-1)&1
        int vo = (L & 1) * 48;
        hipLaunchKernelGGL(k_mv1, dim3(1536), dim3(256), 0, stream,
                           W1h, b1, embb, hbuf,
                           vacc + vi, vacc + vo,
                           vals, visits,
                           nbuf + rs * 16, curbuf + rs * 16,
                           nbuf + wsS * 16, curbuf + wsS * 16, bv, t, fold);
        hipLaunchKernelGGL(k_mv2, dim3(1536), dim3(256), 0, stream,
                           W2h, b2, wv, hbuf, embb,
                           vacc + vo,
                           nbuf + wsS * 16, curbuf + wsS * 16,
                           fold, nbuf + rs * 16, curbuf + rs * 16, vacc + vi,
                           vals, visits, bv);
        ++L;
    }
    // final state after t=124 -> slot 125%3 = 2; pending expansion in vacc slot (100&1)=0
    hipLaunchKernelGGL(kf, dim3(1), dim3(256), 0, stream,
                       embb, vals, visits, nbuf + 32, curbuf + 32, vacc, bv, out);
}

// Round 14
// 3113.445 us; speedup vs baseline: 1.0959x; 1.0959x over previous
//
#include <hip/hip_runtime.h>
#include <hip/hip_fp16.h>

#define Hh 1024
#define H2 2048
#define NB 16
#define MAXN 376
#define NSTAGE 125

__device__ __forceinline__ float gelu_f(float x) {
    return 0.5f * x * (1.0f + erff(x * 0.70710678118654752440f));
}

// ---------------- float -> half conversion (weights into workspace) ----------------
__global__ __launch_bounds__(256) void kcvt(const float* __restrict__ src,
                                            __half* __restrict__ dst, int n) {
    int i = blockIdx.x * 256 + threadIdx.x;
    int stride = gridDim.x * 256;
    for (; i < n; i += stride) dst[i] = __float2half(src[i]);
}

// ---------------- K0a: tmp[b][o] = gelu( concat(p,c) @ Wte + bte ) ----------------
__global__ __launch_bounds__(256) void k0a(const float* __restrict__ Wte,
                                           const float* __restrict__ bte,
                                           const float* __restrict__ pe,
                                           const float* __restrict__ cte,
                                           float* __restrict__ tmp) {
    __shared__ float red[8][8][33];
    int tid = threadIdx.x;
    int ob = blockIdx.x & 31, bg = blockIdx.x >> 5;
    int o_l = tid & 31, kc = tid >> 5;     // 32 outputs x 8 k-chunks
    int o = ob * 32 + o_l;
    float acc[8] = {0.f,0.f,0.f,0.f,0.f,0.f,0.f,0.f};
    const float* src = (kc < 4) ? pe : cte;
    int koff = (kc < 4) ? 0 : 1024;
    int k0 = kc * 256;
    for (int k = k0; k < k0 + 256; k += 4) {
        float w0 = Wte[(size_t)(k + 0) * Hh + o];
        float w1 = Wte[(size_t)(k + 1) * Hh + o];
        float w2 = Wte[(size_t)(k + 2) * Hh + o];
        float w3 = Wte[(size_t)(k + 3) * Hh + o];
#pragma unroll
        for (int bb = 0; bb < 8; ++bb) {
            int b = bg * 8 + bb;
            const float4 x4 = *(const float4*)(src + (size_t)b * Hh + (k - koff));
            acc[bb] = fmaf(w3, x4.w, fmaf(w2, x4.z, fmaf(w1, x4.y, fmaf(w0, x4.x, acc[bb]))));
        }
    }
#pragma unroll
    for (int bb = 0; bb < 8; ++bb) red[kc][bb][o_l] = acc[bb];
    __syncthreads();
    int o2 = tid & 31, bb2 = tid >> 5;
    float s = 0.f;
#pragma unroll
    for (int q = 0; q < 8; ++q) s += red[q][bb2][o2];
    int og = ob * 32 + o2;
    int b = bg * 8 + bb2;
    tmp[(size_t)b * Hh + og] = gelu_f(s + bte[og]);
}

// ---------------- K0b: LayerNorm + root value + state init (one block per b) ----------------
__global__ __launch_bounds__(256) void k0b(const float* __restrict__ tmp,
                                           const float* __restrict__ g,
                                           const float* __restrict__ bl,
                                           const float* __restrict__ wv,
                                           const float* __restrict__ bv,
                                           float* __restrict__ emb,
                                           float* __restrict__ vals,
                                           int* __restrict__ visits,
                                           int* __restrict__ nbuf,
                                           int* __restrict__ curbuf,
                                           float* __restrict__ vacc) {
    __shared__ float red[256];
    int b = blockIdx.x, tid = threadIdx.x;
    for (int q = tid; q < MAXN; q += 256) {
        if (q > 0) { vals[b * MAXN + q] = 0.f; visits[b * MAXN + q] = 0; }
    }
    if (b == 0 && tid < 48) vacc[tid] = 0.f;
    float4 v = *(const float4*)(tmp + (size_t)b * Hh + tid * 4);
    red[tid] = (v.x + v.y) + (v.z + v.w);
    __syncthreads();
    for (int st = 128; st > 0; st >>= 1) { if (tid < st) red[tid] += red[tid + st]; __syncthreads(); }
    float mu = red[0] * (1.0f / 1024.0f);
    __syncthreads();
    float dx0 = v.x - mu, dx1 = v.y - mu, dx2 = v.z - mu, dx3 = v.w - mu;
    red[tid] = (dx0 * dx0 + dx1 * dx1) + (dx2 * dx2 + dx3 * dx3);
    __syncthreads();
    for (int st = 128; st > 0; st >>= 1) { if (tid < st) red[tid] += red[tid + st]; __syncthreads(); }
    float var = red[0] * (1.0f / 1024.0f);
    __syncthreads();
    float rs = rsqrtf(var + 1e-5f);
    int d0 = tid * 4;
    float r0 = g[d0 + 0] * (dx0 * rs) + bl[d0 + 0];
    float r1 = g[d0 + 1] * (dx1 * rs) + bl[d0 + 1];
    float r2 = g[d0 + 2] * (dx2 * rs) + bl[d0 + 2];
    float r3 = g[d0 + 3] * (dx3 * rs) + bl[d0 + 3];
    float4 ro; ro.x = r0; ro.y = r1; ro.z = r2; ro.w = r3;
    *(float4*)(emb + (size_t)b * MAXN * Hh + d0) = ro;
    red[tid] = (r0 * wv[d0] + r1 * wv[d0 + 1]) + (r2 * wv[d0 + 2] + r3 * wv[d0 + 3]);
    __syncthreads();
    for (int st = 128; st > 0; st >>= 1) { if (tid < st) red[tid] += red[tid + st]; __syncthreads(); }
    if (tid == 0) {
        vals[b * MAXN] = red[0] + bv[0];
        visits[b * MAXN] = 1;
        nbuf[b] = 1;
        curbuf[b] = 0;
    }
}

// ---------------- kbook: all sequential MCTS logic, grid 1 ----------------
// fold==1: first perform the skipped dead-stage transition (apply pending expansion from vacc,
// backprop, cur<-0); then this stage has no pending expansion. Else (t>0): apply pending expansion.
// Then UCB selection (d!=0). Writes nbuf/curbuf in place and ctrl {em, curL[16], nL[16]}; zeroes vacc.
__global__ __launch_bounds__(64) void kbook(float* vals, int* visits,
                                            int* nbuf, int* curbuf,
                                            float* vacc, int* ctrl,
                                            const float* __restrict__ bv,
                                            int t, int fold) {
    __shared__ int exArr[NB];
    int tid = threadIdx.x;
    if (tid < NB) {
        int b = tid;
        int n = nbuf[b], cur = curbuf[b];
        float* vb = vals + b * MAXN;
        int* tb = visits + b * MAXN;
        float v0 = vacc[b * 3 + 0], v1 = vacc[b * 3 + 1], v2 = vacc[b * 3 + 2];
        if (fold) {
            bool epA = (n - 1) < (cur + 1) * 3;
            if (epA) {
                if (n + 0 < MAXN) { vb[n + 0] = bv[0] + v0; tb[n + 0] = 1; }
                if (n + 1 < MAXN) { vb[n + 1] = bv[0] + v1; tb[n + 1] = 1; }
                if (n + 2 < MAXN) { vb[n + 2] = bv[0] + v2; tb[n + 2] = 1; }
                n += 3;
            }
            int leaf = min(cur, n - 1);
            float lv = vb[min(leaf, MAXN - 1)];
            int node = leaf;
#pragma unroll
            for (int it = 0; it < 8; ++it) {
                if (node > 0) {
                    int p = (node - 1) / 3;
                    int pc = tb[p];
                    float pcf = (float)pc;
                    vb[p] = (vb[p] * pcf + lv) / (pcf + 1.0f);
                    tb[p] = pc + 1;
                    node = p;
                }
            }
            tb[leaf] += 1;
            cur = 0;
        } else if (t > 0) {
            bool ep = (n - 1) < (cur + 1) * 3;
            if (ep) {
                if (n + 0 < MAXN) { vb[n + 0] = bv[0] + v0; tb[n + 0] = 1; }
                if (n + 1 < MAXN) { vb[n + 1] = bv[0] + v1; tb[n + 1] = 1; }
                if (n + 2 < MAXN) { vb[n + 2] = bv[0] + v2; tb[n + 2] = 1; }
                n += 3;
            }
        }
        int d = t % 5;
        int cur_new = 0;
        if (d != 0) {
            int pv = 0;
#pragma unroll
            for (int i = 0; i < 3; ++i) {
                int pidx = 3 * cur + i;
                if (pidx < n) pv += tb[min(pidx, MAXN - 1)];
            }
            float log_pv = logf((float)(pv > 1 ? pv : 1));
            float best = -INFINITY; int best_idx = cur;
#pragma unroll
            for (int ci = 0; ci < 3; ++ci) {
                int child = 3 * cur + 1 + ci;
                int safe = min(child, MAXN - 1);
                float v = vb[safe]; int cn = tb[safe];
                float cnf = (float)(cn > 1 ? cn : 1);
                float ucb = v + 1.414f * sqrtf(log_pv / cnf);
                if (child < n && ucb > best) { best = ucb; best_idx = child; }
            }
            cur_new = best_idx;
        }
        nbuf[b] = n; curbuf[b] = cur_new;
        ctrl[1 + b] = cur_new;
        ctrl[17 + b] = n;
        exArr[b] = ((n - 1) < (cur_new + 1) * 3) ? 1 : 0;
    }
    __syncthreads();
    if (tid == 0) {
        int m = 0;
        for (int b = 0; b < NB; ++b) if (exArr[b]) m |= (1 << b);
        ctrl[0] = m;
    }
    if (tid < 48) vacc[tid] = 0.f;
}

// ---------------- K1: pure mv1 -> hbuf. W1h fp16 [6144][1024]; 768 blocks x 8 rows ----------------
__global__ __launch_bounds__(256) void k_mv1(const __half* __restrict__ W1h,
                                             const float* __restrict__ b1,
                                             const float* __restrict__ emb,
                                             float* __restrict__ hbuf,
                                             const int* __restrict__ ctrl) {
    __shared__ float red[32][8][17];
    int tid = threadIdx.x;
    int row = tid >> 5, kpos = tid & 31;
    int o = blockIdx.x * 8 + row;           // [0, 6144)
    const __half* wp = W1h + (size_t)o * Hh;
    uint4 wl[4];
#pragma unroll
    for (int j = 0; j < 4; ++j) wl[j] = *(const uint4*)(wp + j * 256 + kpos * 8);
    unsigned em = (unsigned)ctrl[0];
    if (em) {
        const float4* xp[16];
#pragma unroll
        for (int b = 0; b < 16; ++b)
            xp[b] = (const float4*)(emb + (size_t)(b * MAXN + ctrl[1 + b]) * Hh);
        float acc[16];
#pragma unroll
        for (int b = 0; b < 16; ++b) acc[b] = 0.f;
#pragma unroll
        for (int j = 0; j < 4; ++j) {
            union { uint4 u; __half h[8]; } wu; wu.u = wl[j];
            float wf[8];
#pragma unroll
            for (int r = 0; r < 8; ++r) wf[r] = __half2float(wu.h[r]);
            int f4 = j * 64 + kpos * 2;
#pragma unroll
            for (int b = 0; b < 16; ++b) {
                if (em & (1u << b)) {
                    float4 xa = xp[b][f4];
                    float4 xb = xp[b][f4 + 1];
                    acc[b] = fmaf(wf[3], xa.w, fmaf(wf[2], xa.z, fmaf(wf[1], xa.y, fmaf(wf[0], xa.x, acc[b]))));
                    acc[b] = fmaf(wf[7], xb.w, fmaf(wf[6], xb.z, fmaf(wf[5], xb.y, fmaf(wf[4], xb.x, acc[b]))));
                }
            }
        }
        float* rp = red[kpos][row];
#pragma unroll
        for (int b = 0; b < 16; ++b) rp[b] = acc[b];
    }
    __syncthreads();
    if (em && tid < 128) {
        int row2 = tid >> 4, b2 = tid & 15;
        if (em & (1u << b2)) {
            float s = 0.f;
#pragma unroll
            for (int q = 0; q < 32; ++q) s += red[q][row2][b2];
            int og = blockIdx.x * 8 + row2;
            int w = og >> 11, ii = og & 2047;
            float hv = gelu_f(s + b1[og]);
            hbuf[(size_t)(b2 * 3 + w) * H2 + ii] = hv;
        }
    }
}

// ---------------- K2: pure mv2 -> new emb rows + value atomicAdd. 768 blocks x 4 rows ----------------
__global__ __launch_bounds__(256) void k_mv2(const __half* __restrict__ W2h,
                                             const float* __restrict__ b2p,
                                             const float* __restrict__ wv,
                                             const float* __restrict__ hbuf,
                                             float* __restrict__ emb,
                                             float* __restrict__ vacc,
                                             const int* __restrict__ ctrl) {
    __shared__ float red[64][4][17];
    __shared__ float prS[16][5];
    int tid = threadIdx.x;
    int row = tid >> 6, kpos = tid & 63;
    int o = blockIdx.x * 4 + row;            // [0, 3072)
    const __half* wp = W2h + (size_t)o * H2;
    uint4 wl[4];
#pragma unroll
    for (int j = 0; j < 4; ++j) wl[j] = *(const uint4*)(wp + j * 512 + kpos * 8);
    unsigned em = (unsigned)ctrl[0];
    int w = o >> 10;                         // uniform per block (4 | 1024)
    if (em) {
        const float4* hp[16];
#pragma unroll
        for (int b = 0; b < 16; ++b)
            hp[b] = (const float4*)(hbuf + (size_t)(b * 3 + w) * H2);
        float acc[16];
#pragma unroll
        for (int b = 0; b < 16; ++b) acc[b] = 0.f;
#pragma unroll
        for (int j = 0; j < 4; ++j) {
            union { uint4 u; __half h[8]; } wu; wu.u = wl[j];
            float wf[8];
#pragma unroll
            for (int r = 0; r < 8; ++r) wf[r] = __half2float(wu.h[r]);
            int f4 = j * 128 + kpos * 2;
#pragma unroll
            for (int b = 0; b < 16; ++b) {
                if (em & (1u << b)) {
                    float4 ha = hp[b][f4];
                    float4 hb = hp[b][f4 + 1];
                    acc[b] = fmaf(wf[3], ha.w, fmaf(wf[2], ha.z, fmaf(wf[1], ha.y, fmaf(wf[0], ha.x, acc[b]))));
                    acc[b] = fmaf(wf[7], hb.w, fmaf(wf[6], hb.z, fmaf(wf[5], hb.y, fmaf(wf[4], hb.x, acc[b]))));
                }
            }
        }
        float* rp = red[kpos][row];
#pragma unroll
        for (int b = 0; b < 16; ++b) rp[b] = acc[b];
    }
    __syncthreads();
    if (em && tid < 64) {
        int row2 = tid >> 4, b2 = tid & 15;
        int og = blockIdx.x * 4 + row2;
        int w2i = og >> 10, d2 = og & 1023;
        float pr = 0.f;
        if (em & (1u << b2)) {
            float s = 0.f;
#pragma unroll
            for (int q = 0; q < 64; ++q) s += red[q][row2][b2];
            float ce = emb[(size_t)(b2 * MAXN + ctrl[1 + b2]) * Hh + d2];
            float nv = ce + 0.1f * (s + b2p[og]);
            int nidx = ctrl[17 + b2] + w2i;
            if (nidx < MAXN) emb[(size_t)(b2 * MAXN + nidx) * Hh + d2] = nv;
            pr = nv * wv[d2];
        }
        prS[b2][row2] = pr;
    }
    __syncthreads();
    if (em && tid < NB && (em & (1u << tid))) {
        float s = prS[tid][0] + prS[tid][1] + prS[tid][2] + prS[tid][3];
        atomicAdd(&vacc[tid * 3 + w], s);
    }
}

// ---------------- KF: final pending apply + backprop + argmax + outputs ----------------
__global__ __launch_bounds__(256) void kf(const float* __restrict__ emb,
                                          float* vals, int* visits,
                                          const int* __restrict__ nin,
                                          const int* __restrict__ curin,
                                          const float* __restrict__ vacc,
                                          const float* __restrict__ bv,
                                          float* __restrict__ out) {
    __shared__ int nF[NB];
    __shared__ float bval[NB];
    __shared__ int bidx[NB];
    __shared__ float redv[NB][16];
    __shared__ int redi[NB][16];
    __shared__ float mxS;
    int tid = threadIdx.x;
    if (tid < NB) {
        int b = tid;
        int n_old = nin[b], cur_old = curin[b];
        int n_new = n_old;
        bool ep = (n_old - 1) < (cur_old + 1) * 3;
        if (ep) {
            float vn0 = bv[0] + vacc[b * 3 + 0];
            float vn1 = bv[0] + vacc[b * 3 + 1];
            float vn2 = bv[0] + vacc[b * 3 + 2];
            if (n_old + 0 < MAXN) { vals[b * MAXN + n_old + 0] = vn0; visits[b * MAXN + n_old + 0] = 1; }
            if (n_old + 1 < MAXN) { vals[b * MAXN + n_old + 1] = vn1; visits[b * MAXN + n_old + 1] = 1; }
            if (n_old + 2 < MAXN) { vals[b * MAXN + n_old + 2] = vn2; visits[b * MAXN + n_old + 2] = 1; }
            n_new += 3;
        }
        int leaf = min(cur_old, n_new - 1);
        float lv = vals[b * MAXN + leaf];
        int node = leaf;
#pragma unroll
        for (int it = 0; it < 8; ++it) {
            if (node > 0) {
                int p = (node - 1) / 3;
                int pc = visits[b * MAXN + p];
                float pcf = (float)pc;
                vals[b * MAXN + p] = (vals[b * MAXN + p] * pcf + lv) / (pcf + 1.0f);
                visits[b * MAXN + p] = pc + 1;
                node = p;
            }
        }
        visits[b * MAXN + leaf] += 1;
        nF[b] = n_new;
    }
    __syncthreads();
    {
        int b = tid >> 4, q = tid & 15;
        float bv_ = -INFINITY; int bi_ = MAXN;
        int nn = nF[b];
        for (int idx = q; idx < MAXN; idx += 16) {
            float v = (idx < nn) ? vals[b * MAXN + idx] : -INFINITY;
            if (v > bv_ || (v == bv_ && idx < bi_)) { bv_ = v; bi_ = idx; }
        }
        redv[b][q] = bv_; redi[b][q] = bi_;
    }
    __syncthreads();
    if (tid < NB) {
        int b = tid;
        float bb = -INFINITY; int bi = MAXN;
        for (int q = 0; q < 16; ++q) {
            float v = redv[b][q]; int i2 = redi[b][q];
            if (v > bb || (v == bb && i2 < bi)) { bb = v; bi = i2; }
        }
        bval[b] = bb; bidx[b] = bi;
    }
    __syncthreads();
    if (tid == 0) {
        float m = bval[0];
        for (int b = 1; b < NB; ++b) m = fmaxf(m, bval[b]);
        mxS = m;
    }
    __syncthreads();
    if (tid < NB) {
        float c = bval[tid] / (mxS + 1e-8f);
        out[16384 + tid] = fminf(c, 1.0f);
        out[16400 + tid] = bval[tid];
    }
    for (int q2 = tid; q2 < 16384; q2 += 256) {
        int b = q2 >> 10, dd = q2 & 1023;
        out[q2] = emb[(size_t)(b * MAXN + bidx[b]) * Hh + dd];
    }
}

extern "C" void kernel_launch(void* const* d_in, const int* in_sizes, int n_in,
                              void* d_out, int out_size, void* d_ws, size_t ws_size,
                              hipStream_t stream) {
    const float* pe  = (const float*)d_in[0];
    const float* ce  = (const float*)d_in[1];
    const float* Wte = (const float*)d_in[2];
    const float* bte = (const float*)d_in[3];
    const float* gln = (const float*)d_in[4];
    const float* bln = (const float*)d_in[5];
    const float* wv  = (const float*)d_in[6];
    const float* bv  = (const float*)d_in[7];
    const float* W1  = (const float*)d_in[8];
    const float* b1  = (const float*)d_in[9];
    const float* W2  = (const float*)d_in[10];
    const float* b2  = (const float*)d_in[11];
    float* out = (float*)d_out;

    float* ws = (float*)d_ws;
    __half* W1h = (__half*)ws;             // 6144x1024 halfs (3145728 floats)
    __half* W2h = W1h + 6291456;           // 3072x2048 halfs (3145728 floats)
    float* embb = ws + 6291456;            // 16 x 376 x 1024
    float* hbuf = embb + 6160384;          // 16 x 3 x 2048
    float* vacc = hbuf + 98304;            // 16 x 3
    float* tmp  = vacc + 48;               // 16 x 1024
    float* vals = tmp + 16384;             // 16 x 376
    int* visits = (int*)(vals + 6016);     // 16 x 376
    int* nbuf   = visits + 6016;           // 16
    int* curbuf = nbuf + 16;               // 16
    int* ctrl   = curbuf + 16;             // 33 ints {em, curL[16], nL[16]}

    hipLaunchKernelGGL(kcvt, dim3(2048), dim3(256), 0, stream, W1, W1h, 6291456);
    hipLaunchKernelGGL(kcvt, dim3(2048), dim3(256), 0, stream, W2, W2h, 6291456);

    hipLaunchKernelGGL(k0a, dim3(64), dim3(256), 0, stream, Wte, bte, pe, ce, tmp);
    hipLaunchKernelGGL(k0b, dim3(16), dim3(256), 0, stream, tmp, gln, bln, wv, bv,
                       embb, vals, visits, nbuf, curbuf, vacc);

    for (int t = 0; t < NSTAGE; ++t) {
        if (t > 0 && t % 5 == 0) continue;           // dead stage folded into t+1
        int fold = (t % 5 == 1 && t > 1) ? 1 : 0;
        hipLaunchKernelGGL(kbook, dim3(1), dim3(64), 0, stream,
                           vals, visits, nbuf, curbuf, vacc, ctrl, bv, t, fold);
        hipLaunchKernelGGL(k_mv1, dim3(768), dim3(256), 0, stream,
                           W1h, b1, embb, hbuf, ctrl);
        hipLaunchKernelGGL(k_mv2, dim3(768), dim3(256), 0, stream,
                           W2h, b2, wv, hbuf, embb, vacc, ctrl);
    }
    hipLaunchKernelGGL(kf, dim3(1), dim3(256), 0, stream,
                       embb, vals, visits, nbuf, curbuf, vacc, bv, out);
}

// Round 15
// 3082.648 us; speedup vs baseline: 1.1068x; 1.0100x over previous
//
#include <hip/hip_runtime.h>
#include <hip/hip_fp16.h>

#define Hh 1024
#define H2 2048
#define NB 16
#define MAXN 376
#define NSTAGE 125

__device__ __forceinline__ float gelu_f(float x) {
    return 0.5f * x * (1.0f + erff(x * 0.70710678118654752440f));
}

// ---------------- float -> half conversion (weights into workspace) ----------------
__global__ __launch_bounds__(256) void kcvt(const float* __restrict__ src,
                                            __half* __restrict__ dst, int n) {
    int i = blockIdx.x * 256 + threadIdx.x;
    int stride = gridDim.x * 256;
    for (; i < n; i += stride) dst[i] = __float2half(src[i]);
}

// ---------------- K0a: tmp[b][o] = gelu( concat(p,c) @ Wte + bte ) ----------------
__global__ __launch_bounds__(256) void k0a(const float* __restrict__ Wte,
                                           const float* __restrict__ bte,
                                           const float* __restrict__ pe,
                                           const float* __restrict__ cte,
                                           float* __restrict__ tmp) {
    __shared__ float red[8][8][33];
    int tid = threadIdx.x;
    int ob = blockIdx.x & 31, bg = blockIdx.x >> 5;
    int o_l = tid & 31, kc = tid >> 5;     // 32 outputs x 8 k-chunks
    int o = ob * 32 + o_l;
    float acc[8] = {0.f,0.f,0.f,0.f,0.f,0.f,0.f,0.f};
    const float* src = (kc < 4) ? pe : cte;
    int koff = (kc < 4) ? 0 : 1024;
    int k0 = kc * 256;
    for (int k = k0; k < k0 + 256; k += 4) {
        float w0 = Wte[(size_t)(k + 0) * Hh + o];
        float w1 = Wte[(size_t)(k + 1) * Hh + o];
        float w2 = Wte[(size_t)(k + 2) * Hh + o];
        float w3 = Wte[(size_t)(k + 3) * Hh + o];
#pragma unroll
        for (int bb = 0; bb < 8; ++bb) {
            int b = bg * 8 + bb;
            const float4 x4 = *(const float4*)(src + (size_t)b * Hh + (k - koff));
            acc[bb] = fmaf(w3, x4.w, fmaf(w2, x4.z, fmaf(w1, x4.y, fmaf(w0, x4.x, acc[bb]))));
        }
    }
#pragma unroll
    for (int bb = 0; bb < 8; ++bb) red[kc][bb][o_l] = acc[bb];
    __syncthreads();
    int o2 = tid & 31, bb2 = tid >> 5;
    float s = 0.f;
#pragma unroll
    for (int q = 0; q < 8; ++q) s += red[q][bb2][o2];
    int og = ob * 32 + o2;
    int b = bg * 8 + bb2;
    tmp[(size_t)b * Hh + og] = gelu_f(s + bte[og]);
}

// ---------------- K0b: LayerNorm + root value + state init (one block per b) ----------------
__global__ __launch_bounds__(256) void k0b(const float* __restrict__ tmp,
                                           const float* __restrict__ g,
                                           const float* __restrict__ bl,
                                           const float* __restrict__ wv,
                                           const float* __restrict__ bv,
                                           float* __restrict__ emb,
                                           float* __restrict__ vals,
                                           int* __restrict__ visits,
                                           int* __restrict__ nbuf,
                                           int* __restrict__ curbuf,
                                           float* __restrict__ vacc) {
    __shared__ float red[256];
    int b = blockIdx.x, tid = threadIdx.x;
    for (int q = tid; q < MAXN; q += 256) {
        if (q > 0) { vals[b * MAXN + q] = 0.f; visits[b * MAXN + q] = 0; }
    }
    if (b == 0 && tid < 96) vacc[tid] = 0.f;   // both vacc slots
    float4 v = *(const float4*)(tmp + (size_t)b * Hh + tid * 4);
    red[tid] = (v.x + v.y) + (v.z + v.w);
    __syncthreads();
    for (int st = 128; st > 0; st >>= 1) { if (tid < st) red[tid] += red[tid + st]; __syncthreads(); }
    float mu = red[0] * (1.0f / 1024.0f);
    __syncthreads();
    float dx0 = v.x - mu, dx1 = v.y - mu, dx2 = v.z - mu, dx3 = v.w - mu;
    red[tid] = (dx0 * dx0 + dx1 * dx1) + (dx2 * dx2 + dx3 * dx3);
    __syncthreads();
    for (int st = 128; st > 0; st >>= 1) { if (tid < st) red[tid] += red[tid + st]; __syncthreads(); }
    float var = red[0] * (1.0f / 1024.0f);
    __syncthreads();
    float rs = rsqrtf(var + 1e-5f);
    int d0 = tid * 4;
    float r0 = g[d0 + 0] * (dx0 * rs) + bl[d0 + 0];
    float r1 = g[d0 + 1] * (dx1 * rs) + bl[d0 + 1];
    float r2 = g[d0 + 2] * (dx2 * rs) + bl[d0 + 2];
    float r3 = g[d0 + 3] * (dx3 * rs) + bl[d0 + 3];
    float4 ro; ro.x = r0; ro.y = r1; ro.z = r2; ro.w = r3;
    *(float4*)(emb + (size_t)b * MAXN * Hh + d0) = ro;
    red[tid] = (r0 * wv[d0] + r1 * wv[d0 + 1]) + (r2 * wv[d0 + 2] + r3 * wv[d0 + 3]);
    __syncthreads();
    for (int st = 128; st > 0; st >>= 1) { if (tid < st) red[tid] += red[tid + st]; __syncthreads(); }
    if (tid == 0) {
        vals[b * MAXN] = red[0] + bv[0];
        visits[b * MAXN] = 1;
        nbuf[b] = 1;          // state slot 0
        curbuf[b] = 0;
    }
}

// ---------------- K1: replicated bookkeeping (+fold local) + pure-stream mv1 -> hbuf ----------------
// W1h fp16 [6144][1024]; 768 blocks x 8 rows; thread (row=tid>>5, kpos=tid&31), 4 hoisted uint4.
__global__ __launch_bounds__(256) void k_mv1(const __half* __restrict__ W1h,
                                             const float* __restrict__ b1,
                                             const float* __restrict__ emb,
                                             float* __restrict__ hbuf,
                                             const float* __restrict__ vin,
                                             float* __restrict__ vout,
                                             float* vals, int* visits,
                                             const int* __restrict__ nin,
                                             const int* __restrict__ curin,
                                             int* __restrict__ nout,
                                             int* __restrict__ curout,
                                             const float* __restrict__ bv, int t, int fold) {
    __shared__ float red[32][8][17];
    __shared__ int curL[NB];
    __shared__ int exS;
    int tid = threadIdx.x;
    int d = t % 5;
    if (blockIdx.x == 0 && tid < 48) vout[tid] = 0.f;
    // ---- hoisted weight loads (independent of bookkeeping) ----
    int row = tid >> 5, kpos = tid & 31;
    int o = blockIdx.x * 8 + row;           // [0, 6144)
    const __half* wp = W1h + (size_t)o * Hh;
    uint4 wl[4];
#pragma unroll
    for (int j = 0; j < 4; ++j) wl[j] = *(const uint4*)(wp + j * 256 + kpos * 8);
    if (tid == 0) exS = 0;
    __syncthreads();
    if (tid < NB) {
        int b = tid;
        int n_old = nin[b], cur_old = curin[b];
        float val03[4]; int vis03[4];
        bool lcl = false;
        if (fold) {
            // dead-stage transition, replicated locally (commit deferred to k_mv2 block 0)
            bool epA = (n_old - 1) < (cur_old + 1) * 3;
            float a0 = 0.f, a1 = 0.f, a2 = 0.f;
            if (epA) { a0 = bv[0] + vin[b*3+0]; a1 = bv[0] + vin[b*3+1]; a2 = bv[0] + vin[b*3+2]; }
            int nA = n_old + (epA ? 3 : 0);
#pragma unroll
            for (int i = 0; i < 4; ++i) { val03[i] = vals[b*MAXN+i]; vis03[i] = visits[b*MAXN+i]; }
            int leaf = min(cur_old, nA - 1);
            int jl = leaf - n_old;
            float lv;
            if (epA && jl >= 0 && jl < 3) lv = (jl == 0) ? a0 : ((jl == 1) ? a1 : a2);
            else lv = vals[b*MAXN + min(leaf, MAXN-1)];
            int node = leaf;
#pragma unroll
            for (int it2 = 0; it2 < 8; ++it2) {
                if (node > 0) {
                    int p = (node - 1) / 3;
                    int pc; float pvv;
                    if (p < 4) { pc = vis03[p]; pvv = val03[p]; }
                    else { pc = visits[b*MAXN+p]; pvv = vals[b*MAXN+p]; }
                    float pcf = (float)pc;
                    float nvv = (pvv * pcf + lv) / (pcf + 1.0f);
                    if (p < 4) { val03[p] = nvv; vis03[p] = pc + 1; }
                    node = p;
                }
            }
            n_old = nA; cur_old = 0; lcl = true;
        }
        int n_new = n_old;
        bool ep = false;
        float vnew0 = 0.f, vnew1 = 0.f, vnew2 = 0.f;
        if (t > 0 && !fold) {
            ep = (n_old - 1) < (cur_old + 1) * 3;
            if (ep) {
                vnew0 = bv[0] + vin[b*3+0];
                vnew1 = bv[0] + vin[b*3+1];
                vnew2 = bv[0] + vin[b*3+2];
                n_new += 3;
            }
        }
        int cur_new = 0;
        const float* vb = vals + b * MAXN;
        const int* tb = visits + b * MAXN;
        if (d != 0) {
            int pv = 0;
#pragma unroll
            for (int i = 0; i < 3; ++i) {
                int pidx = 3 * cur_old + i;
                if (pidx < n_new) {
                    int safe = min(pidx, MAXN - 1);
                    int jj = safe - n_old;
                    int vis;
                    if (ep && jj >= 0 && jj < 3) vis = 1;
                    else if (lcl && safe < 4) vis = vis03[safe];
                    else vis = tb[safe];
                    pv += vis;
                }
            }
            float log_pv = logf((float)(pv > 1 ? pv : 1));
            float best = -INFINITY; int best_idx = cur_old;
#pragma unroll
            for (int ci = 0; ci < 3; ++ci) {
                int child = 3 * cur_old + 1 + ci;
                int safe = min(child, MAXN - 1);
                int jj = safe - n_old;
                float v; int cn;
                if (ep && jj >= 0 && jj < 3) {
                    v = (jj == 0) ? vnew0 : ((jj == 1) ? vnew1 : vnew2);
                    cn = 1;
                } else if (lcl && safe < 4) {
                    v = val03[safe]; cn = vis03[safe];
                } else { v = vb[safe]; cn = tb[safe]; }
                float cnf = (float)(cn > 1 ? cn : 1);
                float ucb = v + 1.414f * sqrtf(log_pv / cnf);
                if (child < n_new && ucb > best) { best = ucb; best_idx = child; }
            }
            cur_new = best_idx;
        }
        bool ex = (n_new - 1) < (cur_new + 1) * 3;
        curL[b] = cur_new;
        if (ex) atomicOr(&exS, 1 << b);
        if (blockIdx.x == 0) {
            nout[b] = n_new; curout[b] = cur_new;
            if (ep) {
                if (n_old + 0 < MAXN) { vals[b * MAXN + n_old + 0] = vnew0; visits[b * MAXN + n_old + 0] = 1; }
                if (n_old + 1 < MAXN) { vals[b * MAXN + n_old + 1] = vnew1; visits[b * MAXN + n_old + 1] = 1; }
                if (n_old + 2 < MAXN) { vals[b * MAXN + n_old + 2] = vnew2; visits[b * MAXN + n_old + 2] = 1; }
            }
        }
    }
    __syncthreads();
    unsigned em = (unsigned)exS;
    if (em) {
        const float4* xp[16];
#pragma unroll
        for (int b = 0; b < 16; ++b)
            xp[b] = (const float4*)(emb + (size_t)(b * MAXN + curL[b]) * Hh);
        float acc[16];
#pragma unroll
        for (int b = 0; b < 16; ++b) acc[b] = 0.f;
#pragma unroll
        for (int j = 0; j < 4; ++j) {
            union { uint4 u; __half h[8]; } wu; wu.u = wl[j];
            float wf[8];
#pragma unroll
            for (int r = 0; r < 8; ++r) wf[r] = __half2float(wu.h[r]);
            int f4 = j * 64 + kpos * 2;
#pragma unroll
            for (int b = 0; b < 16; ++b) {
                if (em & (1u << b)) {
                    float4 xa = xp[b][f4];
                    float4 xb = xp[b][f4 + 1];
                    acc[b] = fmaf(wf[3], xa.w, fmaf(wf[2], xa.z, fmaf(wf[1], xa.y, fmaf(wf[0], xa.x, acc[b]))));
                    acc[b] = fmaf(wf[7], xb.w, fmaf(wf[6], xb.z, fmaf(wf[5], xb.y, fmaf(wf[4], xb.x, acc[b]))));
                }
            }
        }
        float* rp = red[kpos][row];
#pragma unroll
        for (int b = 0; b < 16; ++b) rp[b] = acc[b];
    }
    __syncthreads();
    if (em && tid < 128) {
        int row2 = tid >> 4, b2 = tid & 15;
        if (em & (1u << b2)) {
            float s = 0.f;
#pragma unroll
            for (int q = 0; q < 32; ++q) s += red[q][row2][b2];
            int og = blockIdx.x * 8 + row2;
            int w = og >> 11, ii = og & 2047;
            float hv = gelu_f(s + b1[og]);
            hbuf[(size_t)(b2 * 3 + w) * H2 + ii] = hv;
        }
    }
}

// ---------------- K2: commit folded transition (block 0) + pure-stream mv2 + value atomicAdd ----------------
// W2h fp16 [3072][2048]; 768 blocks x 4 rows; thread (row=tid>>6, kpos=tid&63), 4 hoisted uint4.
__global__ __launch_bounds__(256) void k_mv2(const __half* __restrict__ W2h,
                                             const float* __restrict__ b2p,
                                             const float* __restrict__ wv,
                                             const float* __restrict__ hbuf,
                                             float* __restrict__ emb,
                                             float* __restrict__ vacc,
                                             const int* __restrict__ nin,
                                             const int* __restrict__ curin,
                                             int foldA,
                                             const int* __restrict__ ninA,
                                             const int* __restrict__ curinA,
                                             const float* __restrict__ vinA,
                                             float* vals, int* visits,
                                             const float* __restrict__ bv) {
    __shared__ float red[64][4][17];
    __shared__ float prS[16][5];
    __shared__ int curL[NB], nL[NB];
    __shared__ int exS;
    int tid = threadIdx.x;
    // ---- hoisted weight loads ----
    int row = tid >> 6, kpos = tid & 63;
    int o = blockIdx.x * 4 + row;            // [0, 3072)
    const __half* wp = W2h + (size_t)o * H2;
    uint4 wl[4];
#pragma unroll
    for (int j = 0; j < 4; ++j) wl[j] = *(const uint4*)(wp + j * 512 + kpos * 8);
    // ---- commit the folded dead-stage transition (single writer) ----
    if (foldA && blockIdx.x == 0 && tid < NB) {
        int b = tid;
        int nO = ninA[b], cO = curinA[b];
        bool epA = (nO - 1) < (cO + 1) * 3;
        if (epA) {
            float a0 = bv[0] + vinA[b*3+0];
            float a1 = bv[0] + vinA[b*3+1];
            float a2 = bv[0] + vinA[b*3+2];
            if (nO + 0 < MAXN) { vals[b*MAXN+nO+0] = a0; visits[b*MAXN+nO+0] = 1; }
            if (nO + 1 < MAXN) { vals[b*MAXN+nO+1] = a1; visits[b*MAXN+nO+1] = 1; }
            if (nO + 2 < MAXN) { vals[b*MAXN+nO+2] = a2; visits[b*MAXN+nO+2] = 1; }
        }
        int nA = nO + (epA ? 3 : 0);
        int leaf = min(cO, nA - 1);
        float lv = vals[b*MAXN + min(leaf, MAXN-1)];
        int node = leaf;
#pragma unroll
        for (int it2 = 0; it2 < 8; ++it2) {
            if (node > 0) {
                int p = (node - 1) / 3;
                int pc = visits[b*MAXN+p];
                float pcf = (float)pc;
                vals[b*MAXN+p] = (vals[b*MAXN+p] * pcf + lv) / (pcf + 1.0f);
                visits[b*MAXN+p] = pc + 1;
                node = p;
            }
        }
        visits[b*MAXN+leaf] += 1;
    }
    if (tid < NB) { curL[tid] = curin[tid]; nL[tid] = nin[tid]; }
    __syncthreads();
    if (tid == 0) {
        int m = 0;
        for (int b = 0; b < NB; ++b)
            if ((nL[b] - 1) < (curL[b] + 1) * 3) m |= 1 << b;
        exS = m;
    }
    __syncthreads();
    unsigned em = (unsigned)exS;
    int w = o >> 10;                         // uniform per block (4 | 1024)
    if (em) {
        const float4* hp[16];
#pragma unroll
        for (int b = 0; b < 16; ++b)
            hp[b] = (const float4*)(hbuf + (size_t)(b * 3 + w) * H2);
        float acc[16];
#pragma unroll
        for (int b = 0; b < 16; ++b) acc[b] = 0.f;
#pragma unroll
        for (int j = 0; j < 4; ++j) {
            union { uint4 u; __half h[8]; } wu; wu.u = wl[j];
            float wf[8];
#pragma unroll
            for (int r = 0; r < 8; ++r) wf[r] = __half2float(wu.h[r]);
            int f4 = j * 128 + kpos * 2;
#pragma unroll
            for (int b = 0; b < 16; ++b) {
                if (em & (1u << b)) {
                    float4 ha = hp[b][f4];
                    float4 hb = hp[b][f4 + 1];
                    acc[b] = fmaf(wf[3], ha.w, fmaf(wf[2], ha.z, fmaf(wf[1], ha.y, fmaf(wf[0], ha.x, acc[b]))));
                    acc[b] = fmaf(wf[7], hb.w, fmaf(wf[6], hb.z, fmaf(wf[5], hb.y, fmaf(wf[4], hb.x, acc[b]))));
                }
            }
        }
        float* rp = red[kpos][row];
#pragma unroll
        for (int b = 0; b < 16; ++b) rp[b] = acc[b];
    }
    __syncthreads();
    if (em && tid < 64) {
        int row2 = tid >> 4, b2 = tid & 15;
        int og = blockIdx.x * 4 + row2;
        int w2i = og >> 10, d2 = og & 1023;
        float pr = 0.f;
        if (em & (1u << b2)) {
            float s = 0.f;
#pragma unroll
            for (int q = 0; q < 64; ++q) s += red[q][row2][b2];
            float ce = emb[(size_t)(b2 * MAXN + curL[b2]) * Hh + d2];
            float nv = ce + 0.1f * (s + b2p[og]);
            int nidx = nL[b2] + w2i;
            if (nidx < MAXN) emb[(size_t)(b2 * MAXN + nidx) * Hh + d2] = nv;
            pr = nv * wv[d2];
        }
        prS[b2][row2] = pr;
    }
    __syncthreads();
    if (em && tid < NB && (em & (1u << tid))) {
        float s = prS[tid][0] + prS[tid][1] + prS[tid][2] + prS[tid][3];
        atomicAdd(&vacc[tid * 3 + w], s);
    }
}

// ---------------- KF: final pending apply + backprop + argmax + outputs ----------------
__global__ __launch_bounds__(256) void kf(const float* __restrict__ emb,
                                          float* vals, int* visits,
                                          const int* __restrict__ nin,
                                          const int* __restrict__ curin,
                                          const float* __restrict__ vacc,
                                          const float* __restrict__ bv,
                                          float* __restrict__ out) {
    __shared__ int nF[NB];
    __shared__ float bval[NB];
    __shared__ int bidx[NB];
    __shared__ float redv[NB][16];
    __shared__ int redi[NB][16];
    __shared__ float mxS;
    int tid = threadIdx.x;
    if (tid < NB) {
        int b = tid;
        int n_old = nin[b], cur_old = curin[b];
        int n_new = n_old;
        bool ep = (n_old - 1) < (cur_old + 1) * 3;
        if (ep) {
            float vn0 = bv[0] + vacc[b * 3 + 0];
            float vn1 = bv[0] + vacc[b * 3 + 1];
            float vn2 = bv[0] + vacc[b * 3 + 2];
            if (n_old + 0 < MAXN) { vals[b * MAXN + n_old + 0] = vn0; visits[b * MAXN + n_old + 0] = 1; }
            if (n_old + 1 < MAXN) { vals[b * MAXN + n_old + 1] = vn1; visits[b * MAXN + n_old + 1] = 1; }
            if (n_old + 2 < MAXN) { vals[b * MAXN + n_old + 2] = vn2; visits[b * MAXN + n_old + 2] = 1; }
            n_new += 3;
        }
        int leaf = min(cur_old, n_new - 1);
        float lv = vals[b * MAXN + leaf];
        int node = leaf;
#pragma unroll
        for (int it = 0; it < 8; ++it) {
            if (node > 0) {
                int p = (node - 1) / 3;
                int pc = visits[b * MAXN + p];
                float pcf = (float)pc;
                vals[b * MAXN + p] = (vals[b * MAXN + p] * pcf + lv) / (pcf + 1.0f);
                visits[b * MAXN + p] = pc + 1;
                node = p;
            }
        }
        visits[b * MAXN + leaf] += 1;
        nF[b] = n_new;
    }
    __syncthreads();
    {
        int b = tid >> 4, q = tid & 15;
        float bv_ = -INFINITY; int bi_ = MAXN;
        int nn = nF[b];
        for (int idx = q; idx < MAXN; idx += 16) {
            float v = (idx < nn) ? vals[b * MAXN + idx] : -INFINITY;
            if (v > bv_ || (v == bv_ && idx < bi_)) { bv_ = v; bi_ = idx; }
        }
        redv[b][q] = bv_; redi[b][q] = bi_;
    }
    __syncthreads();
    if (tid < NB) {
        int b = tid;
        float bb = -INFINITY; int bi = MAXN;
        for (int q = 0; q < 16; ++q) {
            float v = redv[b][q]; int i2 = redi[b][q];
            if (v > bb || (v == bb && i2 < bi)) { bb = v; bi = i2; }
        }
        bval[b] = bb; bidx[b] = bi;
    }
    __syncthreads();
    if (tid == 0) {
        float m = bval[0];
        for (int b = 1; b < NB; ++b) m = fmaxf(m, bval[b]);
        mxS = m;
    }
    __syncthreads();
    if (tid < NB) {
        float c = bval[tid] / (mxS + 1e-8f);
        out[16384 + tid] = fminf(c, 1.0f);
        out[16400 + tid] = bval[tid];
    }
    for (int q2 = tid; q2 < 16384; q2 += 256) {
        int b = q2 >> 10, dd = q2 & 1023;
        out[q2] = emb[(size_t)(b * MAXN + bidx[b]) * Hh + dd];
    }
}

extern "C" void kernel_launch(void* const* d_in, const int* in_sizes, int n_in,
                              void* d_out, int out_size, void* d_ws, size_t ws_size,
                              hipStream_t stream) {
    const float* pe  = (const float*)d_in[0];
    const float* ce  = (const float*)d_in[1];
    const float* Wte = (const float*)d_in[2];
    const float* bte = (const float*)d_in[3];
    const float* gln = (const float*)d_in[4];
    const float* bln = (const float*)d_in[5];
    const float* wv  = (const float*)d_in[6];
    const float* bv  = (const float*)d_in[7];
    const float* W1  = (const float*)d_in[8];
    const float* b1  = (const float*)d_in[9];
    const float* W2  = (const float*)d_in[10];
    const float* b2  = (const float*)d_in[11];
    float* out = (float*)d_out;

    float* ws = (float*)d_ws;
    __half* W1h = (__half*)ws;             // 6144x1024 halfs (3145728 floats)
    __half* W2h = W1h + 6291456;           // 3072x2048 halfs (3145728 floats)
    float* embb = ws + 6291456;            // 16 x 376 x 1024
    float* hbuf = embb + 6160384;          // 16 x 3 x 2048
    float* vacc = hbuf + 98304;            // 2 slots x 16 x 3
    float* tmp  = vacc + 96;               // 16 x 1024
    float* vals = tmp + 16384;             // 16 x 376
    int* visits = (int*)(vals + 6016);     // 16 x 376
    int* nbuf   = visits + 6016;           // 3 x 16 (mod-3 state slots)
    int* curbuf = nbuf + 48;               // 3 x 16

    hipLaunchKernelGGL(kcvt, dim3(2048), dim3(256), 0, stream, W1, W1h, 6291456);
    hipLaunchKernelGGL(kcvt, dim3(2048), dim3(256), 0, stream, W2, W2h, 6291456);

    hipLaunchKernelGGL(k0a, dim3(64), dim3(256), 0, stream, Wte, bte, pe, ce, tmp);
    hipLaunchKernelGGL(k0b, dim3(16), dim3(256), 0, stream, tmp, gln, bln, wv, bv,
                       embb, vals, visits, nbuf, curbuf, vacc);   // writes state slot 0

    int L = 0;
    for (int t = 0; t < NSTAGE; ++t) {
        if (t > 0 && t % 5 == 0) continue;         // dead stage folded into t+1
        int fold = (t % 5 == 1 && t > 1) ? 1 : 0;
        int rs = (fold ? (t - 1) : t) % 3;         // state read slot
        int wsS = (t + 1) % 3;                     // state write slot
        int vi = ((L + 1) & 1) * 48;               // previous stage's accumulator
        int vo = (L & 1) * 48;
        hipLaunchKernelGGL(k_mv1, dim3(768), dim3(256), 0, stream,
                           W1h, b1, embb, hbuf,
                           vacc + vi, vacc + vo,
                           vals, visits,
                           nbuf + rs * 16, curbuf + rs * 16,
                           nbuf + wsS * 16, curbuf + wsS * 16, bv, t, fold);
        hipLaunchKernelGGL(k_mv2, dim3(768), dim3(256), 0, stream,
                           W2h, b2, wv, hbuf, embb,
                           vacc + vo,
                           nbuf + wsS * 16, curbuf + wsS * 16,
                           fold, nbuf + rs * 16, curbuf + rs * 16, vacc + vi,
                           vals, visits, bv);
        ++L;
    }
    // final state after t=124 -> slot 125%3 = 2; pending expansion in vacc slot (100&1)=0
    hipLaunchKernelGGL(kf, dim3(1), dim3(256), 0, stream,
                       embb, vals, visits, nbuf + 32, curbuf + 32, vacc, bv, out);
}

// Round 16
// 3002.866 us; speedup vs baseline: 1.1362x; 1.0266x over previous
//
#include <hip/hip_runtime.h>
#include <hip/hip_fp16.h>

#define Hh 1024
#define H2 2048
#define NB 16
#define MAXN 376
#define NSTAGE 125

__device__ __forceinline__ float gelu_f(float x) {
    return 0.5f * x * (1.0f + erff(x * 0.70710678118654752440f));
}

// ---------------- float -> half conversion (weights into workspace) ----------------
__global__ __launch_bounds__(256) void kcvt(const float* __restrict__ src,
                                            __half* __restrict__ dst, int n) {
    int i = blockIdx.x * 256 + threadIdx.x;
    int stride = gridDim.x * 256;
    for (; i < n; i += stride) dst[i] = __float2half(src[i]);
}

// ---------------- K0a: tmp[b][o] = gelu( concat(p,c) @ Wte + bte ) ----------------
__global__ __launch_bounds__(256) void k0a(const float* __restrict__ Wte,
                                           const float* __restrict__ bte,
                                           const float* __restrict__ pe,
                                           const float* __restrict__ cte,
                                           float* __restrict__ tmp) {
    __shared__ float red[8][8][33];
    int tid = threadIdx.x;
    int ob = blockIdx.x & 31, bg = blockIdx.x >> 5;
    int o_l = tid & 31, kc = tid >> 5;     // 32 outputs x 8 k-chunks
    int o = ob * 32 + o_l;
    float acc[8] = {0.f,0.f,0.f,0.f,0.f,0.f,0.f,0.f};
    const float* src = (kc < 4) ? pe : cte;
    int koff = (kc < 4) ? 0 : 1024;
    int k0 = kc * 256;
    for (int k = k0; k < k0 + 256; k += 4) {
        float w0 = Wte[(size_t)(k + 0) * Hh + o];
        float w1 = Wte[(size_t)(k + 1) * Hh + o];
        float w2 = Wte[(size_t)(k + 2) * Hh + o];
        float w3 = Wte[(size_t)(k + 3) * Hh + o];
#pragma unroll
        for (int bb = 0; bb < 8; ++bb) {
            int b = bg * 8 + bb;
            const float4 x4 = *(const float4*)(src + (size_t)b * Hh + (k - koff));
            acc[bb] = fmaf(w3, x4.w, fmaf(w2, x4.z, fmaf(w1, x4.y, fmaf(w0, x4.x, acc[bb]))));
        }
    }
#pragma unroll
    for (int bb = 0; bb < 8; ++bb) red[kc][bb][o_l] = acc[bb];
    __syncthreads();
    int o2 = tid & 31, bb2 = tid >> 5;
    float s = 0.f;
#pragma unroll
    for (int q = 0; q < 8; ++q) s += red[q][bb2][o2];
    int og = ob * 32 + o2;
    int b = bg * 8 + bb2;
    tmp[(size_t)b * Hh + og] = gelu_f(s + bte[og]);
}

// ---------------- K0b: LayerNorm + root value + state init (one block per b) ----------------
__global__ __launch_bounds__(256) void k0b(const float* __restrict__ tmp,
                                           const float* __restrict__ g,
                                           const float* __restrict__ bl,
                                           const float* __restrict__ wv,
                                           const float* __restrict__ bv,
                                           float* __restrict__ emb,
                                           float* __restrict__ vals,
                                           int* __restrict__ visits,
                                           int* __restrict__ nbuf,
                                           int* __restrict__ curbuf,
                                           float* __restrict__ vacc) {
    __shared__ float red[256];
    int b = blockIdx.x, tid = threadIdx.x;
    for (int q = tid; q < MAXN; q += 256) {
        if (q > 0) { vals[b * MAXN + q] = 0.f; visits[b * MAXN + q] = 0; }
    }
    if (b == 0 && tid < 96) vacc[tid] = 0.f;   // both vacc slots
    float4 v = *(const float4*)(tmp + (size_t)b * Hh + tid * 4);
    red[tid] = (v.x + v.y) + (v.z + v.w);
    __syncthreads();
    for (int st = 128; st > 0; st >>= 1) { if (tid < st) red[tid] += red[tid + st]; __syncthreads(); }
    float mu = red[0] * (1.0f / 1024.0f);
    __syncthreads();
    float dx0 = v.x - mu, dx1 = v.y - mu, dx2 = v.z - mu, dx3 = v.w - mu;
    red[tid] = (dx0 * dx0 + dx1 * dx1) + (dx2 * dx2 + dx3 * dx3);
    __syncthreads();
    for (int st = 128; st > 0; st >>= 1) { if (tid < st) red[tid] += red[tid + st]; __syncthreads(); }
    float var = red[0] * (1.0f / 1024.0f);
    __syncthreads();
    float rs = rsqrtf(var + 1e-5f);
    int d0 = tid * 4;
    float r0 = g[d0 + 0] * (dx0 * rs) + bl[d0 + 0];
    float r1 = g[d0 + 1] * (dx1 * rs) + bl[d0 + 1];
    float r2 = g[d0 + 2] * (dx2 * rs) + bl[d0 + 2];
    float r3 = g[d0 + 3] * (dx3 * rs) + bl[d0 + 3];
    float4 ro; ro.x = r0; ro.y = r1; ro.z = r2; ro.w = r3;
    *(float4*)(emb + (size_t)b * MAXN * Hh + d0) = ro;
    red[tid] = (r0 * wv[d0] + r1 * wv[d0 + 1]) + (r2 * wv[d0 + 2] + r3 * wv[d0 + 3]);
    __syncthreads();
    for (int st = 128; st > 0; st >>= 1) { if (tid < st) red[tid] += red[tid + st]; __syncthreads(); }
    if (tid == 0) {
        vals[b * MAXN] = red[0] + bv[0];
        visits[b * MAXN] = 1;
        nbuf[b] = 1;          // state slot 0
        curbuf[b] = 0;
    }
}

// ---------------- K1: replicated bookkeeping (+fold local) + pure-stream mv1 -> hbuf ----------------
// W1h fp16 [6144][1024]; 768 blocks x 8 rows, XCD-contiguous swizzle:
//   block bx owns rows (bx&7)*768 + (bx>>3)*8 .. +8  (XCD x = bx%8 always touches same 1.5MB chunk)
__global__ __launch_bounds__(256) void k_mv1(const __half* __restrict__ W1h,
                                             const float* __restrict__ b1,
                                             const float* __restrict__ emb,
                                             float* __restrict__ hbuf,
                                             const float* __restrict__ vin,
                                             float* __restrict__ vout,
                                             float* vals, int* visits,
                                             const int* __restrict__ nin,
                                             const int* __restrict__ curin,
                                             int* __restrict__ nout,
                                             int* __restrict__ curout,
                                             const float* __restrict__ bv, int t, int fold) {
    __shared__ float red[32][8][17];
    __shared__ int curL[NB];
    __shared__ int exS;
    int tid = threadIdx.x;
    int d = t % 5;
    if (blockIdx.x == 0 && tid < 48) vout[tid] = 0.f;
    // ---- hoisted weight loads (independent of bookkeeping) ----
    int row = tid >> 5, kpos = tid & 31;
    int obase = (blockIdx.x & 7) * 768 + (blockIdx.x >> 3) * 8;   // XCD-contiguous
    int o = obase + row;                    // [0, 6144)
    const __half* wp = W1h + (size_t)o * Hh;
    uint4 wl[4];
#pragma unroll
    for (int j = 0; j < 4; ++j) wl[j] = *(const uint4*)(wp + j * 256 + kpos * 8);
    if (tid == 0) exS = 0;
    __syncthreads();
    if (tid < NB) {
        int b = tid;
        int n_old = nin[b], cur_old = curin[b];
        float val03[4]; int vis03[4];
        bool lcl = false;
        if (fold) {
            // dead-stage transition, replicated locally (commit deferred to k_mv2 block 0)
            bool epA = (n_old - 1) < (cur_old + 1) * 3;
            float a0 = 0.f, a1 = 0.f, a2 = 0.f;
            if (epA) { a0 = bv[0] + vin[b*3+0]; a1 = bv[0] + vin[b*3+1]; a2 = bv[0] + vin[b*3+2]; }
            int nA = n_old + (epA ? 3 : 0);
#pragma unroll
            for (int i = 0; i < 4; ++i) { val03[i] = vals[b*MAXN+i]; vis03[i] = visits[b*MAXN+i]; }
            int leaf = min(cur_old, nA - 1);
            int jl = leaf - n_old;
            float lv;
            if (epA && jl >= 0 && jl < 3) lv = (jl == 0) ? a0 : ((jl == 1) ? a1 : a2);
            else lv = vals[b*MAXN + min(leaf, MAXN-1)];
            int node = leaf;
#pragma unroll
            for (int it2 = 0; it2 < 8; ++it2) {
                if (node > 0) {
                    int p = (node - 1) / 3;
                    int pc; float pvv;
                    if (p < 4) { pc = vis03[p]; pvv = val03[p]; }
                    else { pc = visits[b*MAXN+p]; pvv = vals[b*MAXN+p]; }
                    float pcf = (float)pc;
                    float nvv = (pvv * pcf + lv) / (pcf + 1.0f);
                    if (p < 4) { val03[p] = nvv; vis03[p] = pc + 1; }
                    node = p;
                }
            }
            n_old = nA; cur_old = 0; lcl = true;
        }
        int n_new = n_old;
        bool ep = false;
        float vnew0 = 0.f, vnew1 = 0.f, vnew2 = 0.f;
        if (t > 0 && !fold) {
            ep = (n_old - 1) < (cur_old + 1) * 3;
            if (ep) {
                vnew0 = bv[0] + vin[b*3+0];
                vnew1 = bv[0] + vin[b*3+1];
                vnew2 = bv[0] + vin[b*3+2];
                n_new += 3;
            }
        }
        int cur_new = 0;
        const float* vb = vals + b * MAXN;
        const int* tb = visits + b * MAXN;
        if (d != 0) {
            int pv = 0;
#pragma unroll
            for (int i = 0; i < 3; ++i) {
                int pidx = 3 * cur_old + i;
                if (pidx < n_new) {
                    int safe = min(pidx, MAXN - 1);
                    int jj = safe - n_old;
                    int vis;
                    if (ep && jj >= 0 && jj < 3) vis = 1;
                    else if (lcl && safe < 4) vis = vis03[safe];
                    else vis = tb[safe];
                    pv += vis;
                }
            }
            float log_pv = logf((float)(pv > 1 ? pv : 1));
            float best = -INFINITY; int best_idx = cur_old;
#pragma unroll
            for (int ci = 0; ci < 3; ++ci) {
                int child = 3 * cur_old + 1 + ci;
                int safe = min(child, MAXN - 1);
                int jj = safe - n_old;
                float v; int cn;
                if (ep && jj >= 0 && jj < 3) {
                    v = (jj == 0) ? vnew0 : ((jj == 1) ? vnew1 : vnew2);
                    cn = 1;
                } else if (lcl && safe < 4) {
                    v = val03[safe]; cn = vis03[safe];
                } else { v = vb[safe]; cn = tb[safe]; }
                float cnf = (float)(cn > 1 ? cn : 1);
                float ucb = v + 1.414f * sqrtf(log_pv / cnf);
                if (child < n_new && ucb > best) { best = ucb; best_idx = child; }
            }
            cur_new = best_idx;
        }
        bool ex = (n_new - 1) < (cur_new + 1) * 3;
        curL[b] = cur_new;
        if (ex) atomicOr(&exS, 1 << b);
        if (blockIdx.x == 0) {
            nout[b] = n_new; curout[b] = cur_new;
            if (ep) {
                if (n_old + 0 < MAXN) { vals[b * MAXN + n_old + 0] = vnew0; visits[b * MAXN + n_old + 0] = 1; }
                if (n_old + 1 < MAXN) { vals[b * MAXN + n_old + 1] = vnew1; visits[b * MAXN + n_old + 1] = 1; }
                if (n_old + 2 < MAXN) { vals[b * MAXN + n_old + 2] = vnew2; visits[b * MAXN + n_old + 2] = 1; }
            }
        }
    }
    __syncthreads();
    unsigned em = (unsigned)exS;
    if (em) {
        const float4* xp[16];
#pragma unroll
        for (int b = 0; b < 16; ++b)
            xp[b] = (const float4*)(emb + (size_t)(b * MAXN + curL[b]) * Hh);
        float acc[16];
#pragma unroll
        for (int b = 0; b < 16; ++b) acc[b] = 0.f;
#pragma unroll
        for (int j = 0; j < 4; ++j) {
            union { uint4 u; __half h[8]; } wu; wu.u = wl[j];
            float wf[8];
#pragma unroll
            for (int r = 0; r < 8; ++r) wf[r] = __half2float(wu.h[r]);
            int f4 = j * 64 + kpos * 2;
#pragma unroll
            for (int b = 0; b < 16; ++b) {
                if (em & (1u << b)) {
                    float4 xa = xp[b][f4];
                    float4 xb = xp[b][f4 + 1];
                    acc[b] = fmaf(wf[3], xa.w, fmaf(wf[2], xa.z, fmaf(wf[1], xa.y, fmaf(wf[0], xa.x, acc[b]))));
                    acc[b] = fmaf(wf[7], xb.w, fmaf(wf[6], xb.z, fmaf(wf[5], xb.y, fmaf(wf[4], xb.x, acc[b]))));
                }
            }
        }
        float* rp = red[kpos][row];
#pragma unroll
        for (int b = 0; b < 16; ++b) rp[b] = acc[b];
    }
    __syncthreads();
    if (em && tid < 128) {
        int row2 = tid >> 4, b2 = tid & 15;
        if (em & (1u << b2)) {
            float s = 0.f;
#pragma unroll
            for (int q = 0; q < 32; ++q) s += red[q][row2][b2];
            int og = obase + row2;
            int w = og >> 11, ii = og & 2047;
            float hv = gelu_f(s + b1[og]);
            hbuf[(size_t)(b2 * 3 + w) * H2 + ii] = hv;
        }
    }
}

// ---------------- K2: commit folded transition (block 0) + pure-stream mv2 + value atomicAdd ----------------
// W2h fp16 [3072][2048]; 768 blocks x 4 rows, XCD-contiguous swizzle:
//   block bx owns rows (bx&7)*384 + (bx>>3)*4 .. +4
__global__ __launch_bounds__(256) void k_mv2(const __half* __restrict__ W2h,
                                             const float* __restrict__ b2p,
                                             const float* __restrict__ wv,
                                             const float* __restrict__ hbuf,
                                             float* __restrict__ emb,
                                             float* __restrict__ vacc,
                                             const int* __restrict__ nin,
                                             const int* __restrict__ curin,
                                             int foldA,
                                             const int* __restrict__ ninA,
                                             const int* __restrict__ curinA,
                                             const float* __restrict__ vinA,
                                             float* vals, int* visits,
                                             const float* __restrict__ bv) {
    __shared__ float red[64][4][17];
    __shared__ float prS[16][5];
    __shared__ int curL[NB], nL[NB];
    __shared__ int exS;
    int tid = threadIdx.x;
    // ---- hoisted weight loads ----
    int row = tid >> 6, kpos = tid & 63;
    int obase = (blockIdx.x & 7) * 384 + (blockIdx.x >> 3) * 4;   // XCD-contiguous
    int o = obase + row;                     // [0, 3072)
    const __half* wp = W2h + (size_t)o * H2;
    uint4 wl[4];
#pragma unroll
    for (int j = 0; j < 4; ++j) wl[j] = *(const uint4*)(wp + j * 512 + kpos * 8);
    // ---- commit the folded dead-stage transition (single writer) ----
    if (foldA && blockIdx.x == 0 && tid < NB) {
        int b = tid;
        int nO = ninA[b], cO = curinA[b];
        bool epA = (nO - 1) < (cO + 1) * 3;
        if (epA) {
            float a0 = bv[0] + vinA[b*3+0];
            float a1 = bv[0] + vinA[b*3+1];
            float a2 = bv[0] + vinA[b*3+2];
            if (nO + 0 < MAXN) { vals[b*MAXN+nO+0] = a0; visits[b*MAXN+nO+0] = 1; }
            if (nO + 1 < MAXN) { vals[b*MAXN+nO+1] = a1; visits[b*MAXN+nO+1] = 1; }
            if (nO + 2 < MAXN) { vals[b*MAXN+nO+2] = a2; visits[b*MAXN+nO+2] = 1; }
        }
        int nA = nO + (epA ? 3 : 0);
        int leaf = min(cO, nA - 1);
        float lv = vals[b*MAXN + min(leaf, MAXN-1)];
        int node = leaf;
#pragma unroll
        for (int it2 = 0; it2 < 8; ++it2) {
            if (node > 0) {
                int p = (node - 1) / 3;
                int pc = visits[b*MAXN+p];
                float pcf = (float)pc;
                vals[b*MAXN+p] = (vals[b*MAXN+p] * pcf + lv) / (pcf + 1.0f);
                visits[b*MAXN+p] = pc + 1;
                node = p;
            }
        }
        visits[b*MAXN+leaf] += 1;
    }
    if (tid < NB) { curL[tid] = curin[tid]; nL[tid] = nin[tid]; }
    __syncthreads();
    if (tid == 0) {
        int m = 0;
        for (int b = 0; b < NB; ++b)
            if ((nL[b] - 1) < (curL[b] + 1) * 3) m |= 1 << b;
        exS = m;
    }
    __syncthreads();
    unsigned em = (unsigned)exS;
    int w = o >> 10;                         // uniform per block (4-row chunks don't cross 1024)
    if (em) {
        const float4* hp[16];
#pragma unroll
        for (int b = 0; b < 16; ++b)
            hp[b] = (const float4*)(hbuf + (size_t)(b * 3 + w) * H2);
        float acc[16];
#pragma unroll
        for (int b = 0; b < 16; ++b) acc[b] = 0.f;
#pragma unroll
        for (int j = 0; j < 4; ++j) {
            union { uint4 u; __half h[8]; } wu; wu.u = wl[j];
            float wf[8];
#pragma unroll
            for (int r = 0; r < 8; ++r) wf[r] = __half2float(wu.h[r]);
            int f4 = j * 128 + kpos * 2;
#pragma unroll
            for (int b = 0; b < 16; ++b) {
                if (em & (1u << b)) {
                    float4 ha = hp[b][f4];
                    float4 hb = hp[b][f4 + 1];
                    acc[b] = fmaf(wf[3], ha.w, fmaf(wf[2], ha.z, fmaf(wf[1], ha.y, fmaf(wf[0], ha.x, acc[b]))));
                    acc[b] = fmaf(wf[7], hb.w, fmaf(wf[6], hb.z, fmaf(wf[5], hb.y, fmaf(wf[4], hb.x, acc[b]))));
                }
            }
        }
        float* rp = red[kpos][row];
#pragma unroll
        for (int b = 0; b < 16; ++b) rp[b] = acc[b];
    }
    __syncthreads();
    if (em && tid < 64) {
        int row2 = tid >> 4, b2 = tid & 15;
        int og = obase + row2;
        int w2i = og >> 10, d2 = og & 1023;
        float pr = 0.f;
        if (em & (1u << b2)) {
            float s = 0.f;
#pragma unroll
            for (int q = 0; q < 64; ++q) s += red[q][row2][b2];
            float ce = emb[(size_t)(b2 * MAXN + curL[b2]) * Hh + d2];
            float nv = ce + 0.1f * (s + b2p[og]);
            int nidx = nL[b2] + w2i;
            if (nidx < MAXN) emb[(size_t)(b2 * MAXN + nidx) * Hh + d2] = nv;
            pr = nv * wv[d2];
        }
        prS[b2][row2] = pr;
    }
    __syncthreads();
    if (em && tid < NB && (em & (1u << tid))) {
        float s = prS[tid][0] + prS[tid][1] + prS[tid][2] + prS[tid][3];
        atomicAdd(&vacc[tid * 3 + w], s);
    }
}

// ---------------- KF: final pending apply + backprop + argmax + outputs ----------------
__global__ __launch_bounds__(256) void kf(const float* __restrict__ emb,
                                          float* vals, int* visits,
                                          const int* __restrict__ nin,
                                          const int* __restrict__ curin,
                                          const float* __restrict__ vacc,
                                          const float* __restrict__ bv,
                                          float* __restrict__ out) {
    __shared__ int nF[NB];
    __shared__ float bval[NB];
    __shared__ int bidx[NB];
    __shared__ float redv[NB][16];
    __shared__ int redi[NB][16];
    __shared__ float mxS;
    int tid = threadIdx.x;
    if (tid < NB) {
        int b = tid;
        int n_old = nin[b], cur_old = curin[b];
        int n_new = n_old;
        bool ep = (n_old - 1) < (cur_old + 1) * 3;
        if (ep) {
            float vn0 = bv[0] + vacc[b * 3 + 0];
            float vn1 = bv[0] + vacc[b * 3 + 1];
            float vn2 = bv[0] + vacc[b * 3 + 2];
            if (n_old + 0 < MAXN) { vals[b * MAXN + n_old + 0] = vn0; visits[b * MAXN + n_old + 0] = 1; }
            if (n_old + 1 < MAXN) { vals[b * MAXN + n_old + 1] = vn1; visits[b * MAXN + n_old + 1] = 1; }
            if (n_old + 2 < MAXN) { vals[b * MAXN + n_old + 2] = vn2; visits[b * MAXN + n_old + 2] = 1; }
            n_new += 3;
        }
        int leaf = min(cur_old, n_new - 1);
        float lv = vals[b * MAXN + leaf];
        int node = leaf;
#pragma unroll
        for (int it = 0; it < 8; ++it) {
            if (node > 0) {
                int p = (node - 1) / 3;
                int pc = visits[b * MAXN + p];
                float pcf = (float)pc;
                vals[b * MAXN + p] = (vals[b * MAXN + p] * pcf + lv) / (pcf + 1.0f);
                visits[b * MAXN + p] = pc + 1;
                node = p;
            }
        }
        visits[b * MAXN + leaf] += 1;
        nF[b] = n_new;
    }
    __syncthreads();
    {
        int b = tid >> 4, q = tid & 15;
        float bv_ = -INFINITY; int bi_ = MAXN;
        int nn = nF[b];
        for (int idx = q; idx < MAXN; idx += 16) {
            float v = (idx < nn) ? vals[b * MAXN + idx] : -INFINITY;
            if (v > bv_ || (v == bv_ && idx < bi_)) { bv_ = v; bi_ = idx; }
        }
        redv[b][q] = bv_; redi[b][q] = bi_;
    }
    __syncthreads();
    if (tid < NB) {
        int b = tid;
        float bb = -INFINITY; int bi = MAXN;
        for (int q = 0; q < 16; ++q) {
            float v = redv[b][q]; int i2 = redi[b][q];
            if (v > bb || (v == bb && i2 < bi)) { bb = v; bi = i2; }
        }
        bval[b] = bb; bidx[b] = bi;
    }
    __syncthreads();
    if (tid == 0) {
        float m = bval[0];
        for (int b = 1; b < NB; ++b) m = fmaxf(m, bval[b]);
        mxS = m;
    }
    __syncthreads();
    if (tid < NB) {
        float c = bval[tid] / (mxS + 1e-8f);
        out[16384 + tid] = fminf(c, 1.0f);
        out[16400 + tid] = bval[tid];
    }
    for (int q2 = tid; q2 < 16384; q2 += 256) {
        int b = q2 >> 10, dd = q2 & 1023;
        out[q2] = emb[(size_t)(b * MAXN + bidx[b]) * Hh + dd];
    }
}

extern "C" void kernel_launch(void* const* d_in, const int* in_sizes, int n_in,
                              void* d_out, int out_size, void* d_ws, size_t ws_size,
                              hipStream_t stream) {
    const float* pe  = (const float*)d_in[0];
    const float* ce  = (const float*)d_in[1];
    const float* Wte = (const float*)d_in[2];
    const float* bte = (const float*)d_in[3];
    const float* gln = (const float*)d_in[4];
    const float* bln = (const float*)d_in[5];
    const float* wv  = (const float*)d_in[6];
    const float* bv  = (const float*)d_in[7];
    const float* W1  = (const float*)d_in[8];
    const float* b1  = (const float*)d_in[9];
    const float* W2  = (const float*)d_in[10];
    const float* b2  = (const float*)d_in[11];
    float* out = (float*)d_out;

    float* ws = (float*)d_ws;
    __half* W1h = (__half*)ws;             // 6144x1024 halfs (3145728 floats)
    __half* W2h = W1h + 6291456;           // 3072x2048 halfs (3145728 floats)
    float* embb = ws + 6291456;            // 16 x 376 x 1024
    float* hbuf = embb + 6160384;          // 16 x 3 x 2048
    float* vacc = hbuf + 98304;            // 2 slots x 16 x 3
    float* tmp  = vacc + 96;               // 16 x 1024
    float* vals = tmp + 16384;             // 16 x 376
    int* visits = (int*)(vals + 6016);     // 16 x 376
    int* nbuf   = visits + 6016;           // 3 x 16 (mod-3 state slots)
    int* curbuf = nbuf + 48;               // 3 x 16

    hipLaunchKernelGGL(kcvt, dim3(2048), dim3(256), 0, stream, W1, W1h, 6291456);
    hipLaunchKernelGGL(kcvt, dim3(2048), dim3(256), 0, stream, W2, W2h, 6291456);

    hipLaunchKernelGGL(k0a, dim3(64), dim3(256), 0, stream, Wte, bte, pe, ce, tmp);
    hipLaunchKernelGGL(k0b, dim3(16), dim3(256), 0, stream, tmp, gln, bln, wv, bv,
                       embb, vals, visits, nbuf, curbuf, vacc);   // writes state slot 0

    int L = 0;
    for (int t = 0; t < NSTAGE; ++t) {
        if (t > 0 && t % 5 == 0) continue;         // dead stage folded into t+1
        int fold = (t % 5 == 1 && t > 1) ? 1 : 0;
        int rs = (fold ? (t - 1) : t) % 3;         // state read slot
        int wsS = (t + 1) % 3;                     // state write slot
        int vi = ((L + 1) & 1) * 48;               // previous stage's accumulator
        int vo = (L & 1) * 48;
        hipLaunchKernelGGL(k_mv1, dim3(768), dim3(256), 0, stream,
                           W1h, b1, embb, hbuf,
                           vacc + vi, vacc + vo,
                           vals, visits,
                           nbuf + rs * 16, curbuf + rs * 16,
                           nbuf + wsS * 16, curbuf + wsS * 16, bv, t, fold);
        hipLaunchKernelGGL(k_mv2, dim3(768), dim3(256), 0, stream,
                           W2h, b2, wv, hbuf, embb,
                           vacc + vo,
                           nbuf + wsS * 16, curbuf + wsS * 16,
                           fold, nbuf + rs * 16, curbuf + rs * 16, vacc + vi,
                           vals, visits, bv);
        ++L;
    }
    // final state after t=124 -> slot 125%3 = 2; pending expansion in vacc slot (100&1)=0
    hipLaunchKernelGGL(kf, dim3(1), dim3(256), 0, stream,
                       embb, vals, visits, nbuf + 32, curbuf + 32, vacc, bv, out);
}